// Round 1
// baseline (1002.784 us; speedup 1.0000x reference)
//
#include <hip/hip_runtime.h>
#include <hip/hip_bf16.h>

#define NPTS 4096
#define KNN  32
#define LSZ  36   // per-part list size (>= 33), 4 groups of 9

// ---------------- Kernel 1: KNN (top-33 incl self, self dropped at merge) ----
// grid: B*N/64 = 256 blocks, block 256 = 64 rows x 4 parts
__global__ __launch_bounds__(256) void knn_kernel(const float* __restrict__ x,
                                                  int* __restrict__ knn_out)
{
    __shared__ float4 pts4[512];
    __shared__ float  vals[256 * LSZ];
    __shared__ unsigned short inds[256 * LSZ];

    const int t    = threadIdx.x;
    const int b    = blockIdx.x >> 6;
    const int n0   = (blockIdx.x & 63) << 6;
    const int row  = t & 63;
    const int part = t >> 6;
    const int n    = n0 + row;

    const float* xb = x + (size_t)b * 3 * NPTS;
    const float px = xb[n];
    const float py = xb[NPTS + n];
    const float pz = xb[2 * NPTS + n];
    const float sqn = px * px + py * py + pz * pz;

    float* myv = vals + t * LSZ;
    unsigned short* myi = inds + t * LSZ;
    #pragma unroll
    for (int i = 0; i < LSZ; ++i) myv[i] = 3.4e38f;

    float gmax[4]; int gslot[4];
    #pragma unroll
    for (int g = 0; g < 4; ++g) { gmax[g] = 3.4e38f; gslot[g] = g * 9; }
    float worst = 3.4e38f;

    for (int ch = 0; ch < 8; ++ch) {
        __syncthreads();
        #pragma unroll
        for (int r = 0; r < 2; ++r) {
            int it = t + r * 256;
            int j = ch * 512 + it;
            float qx = xb[j], qy = xb[NPTS + j], qz = xb[2 * NPTS + j];
            pts4[it] = make_float4(qx, qy, qz, qx * qx + qy * qy + qz * qz);
        }
        __syncthreads();
        const int base = part * 128;
        for (int s = 0; s < 128; s += 8) {
            float dm[8];
            #pragma unroll
            for (int u = 0; u < 8; ++u) {
                float4 q = pts4[base + s + u];
                dm[u] = (sqn + q.w) - 2.0f * (px * q.x + py * q.y + pz * q.z);
            }
            #pragma unroll
            for (int u = 0; u < 8; ++u) {
                if (dm[u] < worst) {
                    // find group holding current worst
                    int g = 0; float m = gmax[0];
                    if (gmax[1] > m) { m = gmax[1]; g = 1; }
                    if (gmax[2] > m) { m = gmax[2]; g = 2; }
                    if (gmax[3] > m) { m = gmax[3]; g = 3; }
                    int slot = gslot[0];
                    if (g == 1) slot = gslot[1];
                    if (g == 2) slot = gslot[2];
                    if (g == 3) slot = gslot[3];
                    myv[slot] = dm[u];
                    myi[slot] = (unsigned short)(ch * 512 + base + s + u);
                    // rescan the 9-slot group
                    float nm = -3.4e38f; int ns = g * 9;
                    #pragma unroll
                    for (int q2 = 0; q2 < 9; ++q2) {
                        float v = myv[g * 9 + q2];
                        if (v > nm) { nm = v; ns = g * 9 + q2; }
                    }
                    #pragma unroll
                    for (int q2 = 0; q2 < 4; ++q2)
                        if (q2 == g) { gmax[q2] = nm; gslot[q2] = ns; }
                    worst = fmaxf(fmaxf(gmax[0], gmax[1]), fmaxf(gmax[2], gmax[3]));
                }
            }
        }
    }
    // insertion-sort own list ascending by (val, idx) - matches jax top_k tie order
    for (int i = 1; i < LSZ; ++i) {
        float v = myv[i]; unsigned short id = myi[i];
        int j = i - 1;
        while (j >= 0) {
            float vj = myv[j]; unsigned short ij = myi[j];
            if (vj > v || (vj == v && ij > id)) { myv[j + 1] = vj; myi[j + 1] = ij; --j; }
            else break;
        }
        myv[j + 1] = v; myi[j + 1] = id;
    }
    __syncthreads();
    if (t < 64) {  // 4-way merge; first merged element (self / rank-0) dropped
        int p0 = 0, p1 = 0, p2 = 0, p3 = 0;
        int* op = knn_out + ((size_t)b * NPTS + (n0 + t)) * KNN;
        for (int kk = -1; kk < KNN; ++kk) {
            float bv = 3.5e38f; unsigned short bi = 0; int bp = 0;
            if (p0 < LSZ) { float v = vals[t * LSZ + p0]; unsigned short id = inds[t * LSZ + p0];
                if (v < bv || (v == bv && id < bi)) { bv = v; bi = id; bp = 0; } }
            if (p1 < LSZ) { float v = vals[(64 + t) * LSZ + p1]; unsigned short id = inds[(64 + t) * LSZ + p1];
                if (v < bv || (v == bv && id < bi)) { bv = v; bi = id; bp = 1; } }
            if (p2 < LSZ) { float v = vals[(128 + t) * LSZ + p2]; unsigned short id = inds[(128 + t) * LSZ + p2];
                if (v < bv || (v == bv && id < bi)) { bv = v; bi = id; bp = 2; } }
            if (p3 < LSZ) { float v = vals[(192 + t) * LSZ + p3]; unsigned short id = inds[(192 + t) * LSZ + p3];
                if (v < bv || (v == bv && id < bi)) { bv = v; bi = id; bp = 3; } }
            if (bp == 0) ++p0; else if (bp == 1) ++p1; else if (bp == 2) ++p2; else ++p3;
            if (kk >= 0) op[kk] = (int)bi;
        }
    }
}

// ---------------- Kernel 2: per-point 3-layer MLP (one scale per block) ------
// grid: (B*N/32, 3), block 256. F layout [B][N][384], channel = s*128+o
__global__ __launch_bounds__(256) void pointmlp_kernel(
    const float* __restrict__ x,
    const float* __restrict__ sW0, const float* __restrict__ sb0,
    const float* __restrict__ sW1, const float* __restrict__ sb1,
    const float* __restrict__ sW2, const float* __restrict__ sb2,
    float* __restrict__ F)
{
    __shared__ __align__(16) float BUF[8192]; // phaseA: W0[0..192)|b0[192..256)|W1t[256..4352)|h0[4352..6656) ; phaseB: W2t[8192]
    __shared__ __align__(16) float h1s[64 * 36];
    __shared__ float b1s[64];
    __shared__ float b2s[128];
    __shared__ float pts[3 * 33];

    const int t = threadIdx.x;
    const int s = blockIdx.y;
    const int tile = blockIdx.x;
    const int b = tile >> 7;
    const int j0 = (tile & 127) << 5;
    const float* xb = x + (size_t)b * 3 * NPTS;

    if (t < 192) BUF[t] = sW0[s * 192 + t];
    else if (t < 256) BUF[t] = sb0[s * 64 + (t - 192)];
    if (t < 64) b1s[t] = sb1[s * 64 + t];
    if (t < 128) b2s[t] = sb2[s * 128 + t];
    if (t < 96) { int c = t >> 5, p = t & 31; pts[c * 33 + p] = xb[c * NPTS + j0 + p]; }
    {
        const float* W1 = sW1 + (size_t)s * 4096;
        int o = t & 63, q = t >> 6;
        #pragma unroll
        for (int r = 0; r < 4; ++r) {
            float4 w = *(const float4*)(W1 + o * 64 + q * 16 + r * 4);
            int i = q * 16 + r * 4;
            BUF[256 + (i + 0) * 64 + o] = w.x;
            BUF[256 + (i + 1) * 64 + o] = w.y;
            BUF[256 + (i + 2) * 64 + o] = w.z;
            BUF[256 + (i + 3) * 64 + o] = w.w;
        }
    }
    __syncthreads();
    const int o = t & 63, pg = t >> 6;
    float* h0 = BUF + 4352;
    {   // layer 1: 3 -> 64
        float w0 = BUF[o * 3], w1 = BUF[o * 3 + 1], w2 = BUF[o * 3 + 2], bb = BUF[192 + o];
        #pragma unroll
        for (int p = 0; p < 8; ++p) {
            int pp = pg * 8 + p;
            float a = bb + w0 * pts[pp] + w1 * pts[33 + pp] + w2 * pts[66 + pp];
            h0[o * 36 + pp] = fmaxf(a, 0.0f);
        }
    }
    __syncthreads();
    {   // layer 2: 64 -> 64
        float acc[8];
        #pragma unroll
        for (int p = 0; p < 8; ++p) acc[p] = b1s[o];
        for (int i = 0; i < 64; ++i) {
            float w = BUF[256 + i * 64 + o];
            float4 ha = *(const float4*)&h0[i * 36 + pg * 8];
            float4 hb = *(const float4*)&h0[i * 36 + pg * 8 + 4];
            acc[0] += w * ha.x; acc[1] += w * ha.y; acc[2] += w * ha.z; acc[3] += w * ha.w;
            acc[4] += w * hb.x; acc[5] += w * hb.y; acc[6] += w * hb.z; acc[7] += w * hb.w;
        }
        #pragma unroll
        for (int p = 0; p < 8; ++p) h1s[o * 36 + pg * 8 + p] = fmaxf(acc[p], 0.0f);
    }
    __syncthreads();
    {   // restage: W2t over the whole BUF (W0/W1t/h0 dead)
        const float* W2 = sW2 + (size_t)s * 8192;
        int o2 = t & 127, q = t >> 7;
        #pragma unroll
        for (int r = 0; r < 8; ++r) {
            float4 w = *(const float4*)(W2 + o2 * 64 + q * 32 + r * 4);
            int i = q * 32 + r * 4;
            BUF[(i + 0) * 128 + o2] = w.x;
            BUF[(i + 1) * 128 + o2] = w.y;
            BUF[(i + 2) * 128 + o2] = w.z;
            BUF[(i + 3) * 128 + o2] = w.w;
        }
    }
    __syncthreads();
    {   // layer 3: 64 -> 128, coalesced F writes (lanes vary o2)
        int o2 = t & 127, ph = t >> 7;
        float acc[16];
        #pragma unroll
        for (int p = 0; p < 16; ++p) acc[p] = b2s[o2];
        for (int i = 0; i < 64; ++i) {
            float w = BUF[i * 128 + o2];
            float4 ha = *(const float4*)&h1s[i * 36 + ph * 16];
            float4 hb = *(const float4*)&h1s[i * 36 + ph * 16 + 4];
            float4 hc = *(const float4*)&h1s[i * 36 + ph * 16 + 8];
            float4 hd = *(const float4*)&h1s[i * 36 + ph * 16 + 12];
            acc[0]  += w * ha.x; acc[1]  += w * ha.y; acc[2]  += w * ha.z; acc[3]  += w * ha.w;
            acc[4]  += w * hb.x; acc[5]  += w * hb.y; acc[6]  += w * hb.z; acc[7]  += w * hb.w;
            acc[8]  += w * hc.x; acc[9]  += w * hc.y; acc[10] += w * hc.z; acc[11] += w * hc.w;
            acc[12] += w * hd.x; acc[13] += w * hd.y; acc[14] += w * hd.z; acc[15] += w * hd.w;
        }
        #pragma unroll
        for (int p = 0; p < 16; ++p) {
            int j = j0 + ph * 16 + p;
            F[((size_t)b * NPTS + j) * 384 + s * 128 + o2] = fmaxf(acc[p], 0.0f);
        }
    }
}

// ---------------- Kernel 3: gather-max over 32 neighbors + transpose ---------
// grid: (B*N/64, 6 channel-chunks), block 256. point layout [B][384][N]
__global__ __launch_bounds__(256) void maxgather_kernel(
    const float* __restrict__ F, const int* __restrict__ knn,
    float* __restrict__ point)
{
    __shared__ int idxS[64 * KNN];
    __shared__ float T[64 * 65];
    const int t = threadIdx.x;
    const int b = blockIdx.x >> 6;
    const int n0 = (blockIdx.x & 63) << 6;
    const int cc = blockIdx.y;

    #pragma unroll
    for (int r = 0; r < 8; ++r) {
        int lin = t + r * 256;
        idxS[lin] = knn[((size_t)b * NPTS + n0) * KNN + lin];
    }
    __syncthreads();
    const int w = t >> 6, lane = t & 63;
    const float* Fb = F + (size_t)b * NPTS * 384 + cc * 64 + lane;
    #pragma unroll
    for (int g = 0; g < 2; ++g) {
        float m[8];
        #pragma unroll
        for (int u = 0; u < 8; ++u) m[u] = 0.0f;   // post-relu features are >= 0
        int nb_ = w * 16 + g * 8;
        for (int k = 0; k < KNN; ++k) {
            #pragma unroll
            for (int u = 0; u < 8; ++u) {
                int j = idxS[(nb_ + u) * KNN + k];
                float v = Fb[(size_t)j * 384];
                m[u] = fmaxf(m[u], v);
            }
        }
        #pragma unroll
        for (int u = 0; u < 8; ++u) T[lane * 65 + nb_ + u] = m[u];
    }
    __syncthreads();
    #pragma unroll
    for (int r = 0; r < 16; ++r) {
        int lin = t + r * 256;
        int c = lin >> 6, nl = lin & 63;
        point[((size_t)b * 384 + cc * 64 + c) * NPTS + n0 + nl] = T[c * 65 + nl];
    }
}

// ---------------- Kernel 4: fp32 GEMM + bias + relu --------------------------
// C[b][M][N] = relu(W[M][K] * Bm[b][K][N] + bias), tiles 128x128x16, micro 8x8
__global__ __launch_bounds__(256) void gemm_kernel(
    const float* __restrict__ W, const float* __restrict__ Bm,
    const float* __restrict__ bias, float* __restrict__ out,
    int M, int K)
{
    __shared__ __align__(16) float At[16 * 132];
    __shared__ __align__(16) float Bt[16 * 132];
    __shared__ float biasS[128];

    const int t = threadIdx.x;
    const int b = blockIdx.z;
    const int m0 = blockIdx.x * 128;
    const int n0 = blockIdx.y * 128;
    const int tx = t & 15, ty = t >> 4;

    if (t < 128) biasS[t] = bias[m0 + t];

    const float* Wp = W + (size_t)(m0 + (t & 127)) * K + ((t >> 7) * 8);
    const float* Bp = Bm + (size_t)b * K * NPTS + n0;
    const int kb1 = t >> 5, nb1 = (t & 31) * 4;
    const int kb2 = kb1 + 8;

    float acc[64];
    #pragma unroll
    for (int i = 0; i < 64; ++i) acc[i] = 0.0f;

    for (int k0 = 0; k0 < K; k0 += 16) {
        float4 a0 = *(const float4*)(Wp + k0);
        float4 a1 = *(const float4*)(Wp + k0 + 4);
        float4 bv0 = *(const float4*)(Bp + (size_t)(k0 + kb1) * NPTS + nb1);
        float4 bv1 = *(const float4*)(Bp + (size_t)(k0 + kb2) * NPTS + nb1);
        __syncthreads();
        {
            int m = t & 127, kq = (t >> 7) * 8;
            At[(kq + 0) * 132 + m] = a0.x;
            At[(kq + 1) * 132 + m] = a0.y;
            At[(kq + 2) * 132 + m] = a0.z;
            At[(kq + 3) * 132 + m] = a0.w;
            At[(kq + 4) * 132 + m] = a1.x;
            At[(kq + 5) * 132 + m] = a1.y;
            At[(kq + 6) * 132 + m] = a1.z;
            At[(kq + 7) * 132 + m] = a1.w;
            *(float4*)&Bt[kb1 * 132 + nb1] = bv0;
            *(float4*)&Bt[kb2 * 132 + nb1] = bv1;
        }
        __syncthreads();
        #pragma unroll
        for (int k = 0; k < 16; ++k) {
            float4 av0 = *(const float4*)&At[k * 132 + ty * 4];
            float4 av1 = *(const float4*)&At[k * 132 + 64 + ty * 4];
            float4 bw0 = *(const float4*)&Bt[k * 132 + tx * 4];
            float4 bw1 = *(const float4*)&Bt[k * 132 + 64 + tx * 4];
            float ar[8] = {av0.x, av0.y, av0.z, av0.w, av1.x, av1.y, av1.z, av1.w};
            float br[8] = {bw0.x, bw0.y, bw0.z, bw0.w, bw1.x, bw1.y, bw1.z, bw1.w};
            #pragma unroll
            for (int r = 0; r < 8; ++r)
                #pragma unroll
                for (int c = 0; c < 8; ++c)
                    acc[r * 8 + c] += ar[r] * br[c];
        }
    }
    #pragma unroll
    for (int rq = 0; rq < 2; ++rq)
    #pragma unroll
    for (int r = 0; r < 4; ++r) {
        int mm = rq * 64 + ty * 4 + r;
        float bs = biasS[mm];
        float* orow = out + ((size_t)b * M + m0 + mm) * NPTS + n0;
        int ra = rq * 4 + r;
        float4 o0, o1;
        o0.x = fmaxf(acc[ra * 8 + 0] + bs, 0.0f);
        o0.y = fmaxf(acc[ra * 8 + 1] + bs, 0.0f);
        o0.z = fmaxf(acc[ra * 8 + 2] + bs, 0.0f);
        o0.w = fmaxf(acc[ra * 8 + 3] + bs, 0.0f);
        o1.x = fmaxf(acc[ra * 8 + 4] + bs, 0.0f);
        o1.y = fmaxf(acc[ra * 8 + 5] + bs, 0.0f);
        o1.z = fmaxf(acc[ra * 8 + 6] + bs, 0.0f);
        o1.w = fmaxf(acc[ra * 8 + 7] + bs, 0.0f);
        *(float4*)(orow + tx * 4) = o0;
        *(float4*)(orow + 64 + tx * 4) = o1;
    }
}

// ---------------- Kernel 5: row max of gf -> global_feature ------------------
__global__ __launch_bounds__(256) void rowmax_kernel(const float* __restrict__ gf,
                                                     float* __restrict__ outv)
{
    const int wid = threadIdx.x >> 6, lane = threadIdx.x & 63;
    const int row = blockIdx.x * 4 + wid;
    const float4* p = (const float4*)(gf + (size_t)row * NPTS);
    float m = 0.0f;   // gf is post-relu, >= 0
    #pragma unroll
    for (int i = 0; i < 16; ++i) {
        float4 v = p[lane + i * 64];
        m = fmaxf(m, fmaxf(fmaxf(v.x, v.y), fmaxf(v.z, v.w)));
    }
    #pragma unroll
    for (int off = 32; off > 0; off >>= 1)
        m = fmaxf(m, __shfl_xor(m, off, 64));
    if (lane == 0) outv[row] = m;
}

extern "C" void kernel_launch(void* const* d_in, const int* in_sizes, int n_in,
                              void* d_out, int out_size, void* d_ws, size_t ws_size,
                              hipStream_t stream)
{
    const float* x   = (const float*)d_in[0];
    const float* sW0 = (const float*)d_in[1];
    const float* sb0 = (const float*)d_in[2];
    const float* sW1 = (const float*)d_in[3];
    const float* sb1 = (const float*)d_in[4];
    const float* sW2 = (const float*)d_in[5];
    const float* sb2 = (const float*)d_in[6];
    const float* gW0 = (const float*)d_in[7];
    const float* gb0 = (const float*)d_in[8];
    const float* gW1 = (const float*)d_in[9];
    const float* gb1 = (const float*)d_in[10];
    const float* mW0 = (const float*)d_in[11];
    const float* mb0 = (const float*)d_in[12];
    const float* mW1 = (const float*)d_in[13];
    const float* mb1 = (const float*)d_in[14];
    float* outp = (float*)d_out;

    char* ws = (char*)d_ws;
    int*   idx   = (int*)(ws);                       // 2 MB
    float* F     = (float*)(ws + 2097152u);          // 25.2 MB  [B][N][384]
    float* point = (float*)(ws + 27262976u);         // 25.2 MB  [B][384][N]
    float* gf0   = (float*)(ws + 52428800u);         // 16.8 MB  [B][256][N]
    float* gf    = (float*)(ws + 69206016u);         // 67.1 MB  [B][1024][N]
    float* msf0  = (float*)(ws + 2097152u);          // aliases F (dead by then)

    hipLaunchKernelGGL(knn_kernel, dim3(256), dim3(256), 0, stream, x, idx);
    hipLaunchKernelGGL(pointmlp_kernel, dim3(512, 3), dim3(256), 0, stream,
                       x, sW0, sb0, sW1, sb1, sW2, sb2, F);
    hipLaunchKernelGGL(maxgather_kernel, dim3(256, 6), dim3(256), 0, stream, F, idx, point);
    hipLaunchKernelGGL(gemm_kernel, dim3(2, 32, 4), dim3(256), 0, stream,
                       gW0, point, gb0, gf0, 256, 384);
    hipLaunchKernelGGL(gemm_kernel, dim3(8, 32, 4), dim3(256), 0, stream,
                       gW1, gf0, gb1, gf, 1024, 256);
    hipLaunchKernelGGL(rowmax_kernel, dim3(1024), dim3(256), 0, stream, gf, outp);
    hipLaunchKernelGGL(gemm_kernel, dim3(2, 32, 4), dim3(256), 0, stream,
                       mW0, gf, mb0, msf0, 256, 1024);
    hipLaunchKernelGGL(gemm_kernel, dim3(1, 32, 4), dim3(256), 0, stream,
                       mW1, msf0, mb1, outp + 4096, 128, 256);
}

// Round 2
// 741.107 us; speedup vs baseline: 1.3531x; 1.3531x over previous
//
#include <hip/hip_runtime.h>
#include <hip/hip_bf16.h>

#define NPTS 4096
#define KNN  32
#define KSEL 33   // select 33 smallest (incl. self), drop the minimum

// ---------------- Kernel 1: exact KNN via rank-33 binary search on key bits --
// grid: B*N = 16384 blocks, 256 threads; 16 candidates/thread in registers.
__global__ __launch_bounds__(256) void knn_kernel2(const float* __restrict__ x,
                                                   int* __restrict__ knn_out)
{
    __shared__ unsigned int sb[2][4];
    __shared__ int lt_idx[40];
    __shared__ unsigned int lt_key[40];
    __shared__ int eq_idx[64];
    __shared__ unsigned int lt_cnt, eq_cnt;

    const int t = threadIdx.x;
    const int q = blockIdx.x;
    const int b = q >> 12;
    const int n = q & (NPTS - 1);
    const float* xb = x + (size_t)b * 3 * NPTS;

    const float px = xb[n], py = xb[NPTS + n], pz = xb[2 * NPTS + n];
    const float sqn = px * px + py * py + pz * pz;

    // distances -> monotone uint keys, kept in registers (no LDS)
    unsigned int key[16];
    #pragma unroll
    for (int r = 0; r < 16; ++r) {
        int j = t + (r << 8);
        float qx = xb[j], qy = xb[NPTS + j], qz = xb[2 * NPTS + j];
        float sqj = qx * qx + qy * qy + qz * qz;
        float d = (sqn + sqj) - 2.0f * (px * qx + py * qy + pz * qz);
        unsigned int u = __float_as_uint(d);
        key[r] = (u & 0x80000000u) ? ~u : (u | 0x80000000u);
    }
    if (t == 0) { lt_cnt = 0u; eq_cnt = 0u; }
    const int wid = t >> 6;
    const int lane = t & 63;

    // binary search: smallest T with g(T) = #{key <= T} >= 33  (exact 33rd key)
    unsigned int lo = 0u, hi = 0xFFFFFFFFu;
    for (int it = 0; it < 32; ++it) {
        unsigned int mid = lo + ((hi - lo) >> 1);
        unsigned int cnt = 0;
        #pragma unroll
        for (int r = 0; r < 16; ++r)
            cnt += (unsigned int)__popcll(__ballot(key[r] <= mid));
        if (lane == 0) sb[it & 1][wid] = cnt;
        __syncthreads();
        unsigned int g = sb[it & 1][0] + sb[it & 1][1] + sb[it & 1][2] + sb[it & 1][3];
        if (g >= 33u) hi = mid; else lo = mid + 1u;
        // all threads follow identical lo/hi trajectory -> no broadcast needed
    }
    const unsigned int T = lo;

    // collect: keys < T (at most 32 of them) and keys == T
    #pragma unroll
    for (int r = 0; r < 16; ++r) {
        int j = t + (r << 8);
        if (key[r] < T) {
            unsigned int p = atomicAdd(&lt_cnt, 1u);
            if (p < 40u) { lt_idx[p] = j; lt_key[p] = key[r]; }
        } else if (key[r] == T) {
            unsigned int p = atomicAdd(&eq_cnt, 1u);
            if (p < 64u) eq_idx[p] = j;
        }
    }
    __syncthreads();

    if (t == 0) {
        int nlt = (int)lt_cnt; if (nlt > 40) nlt = 40;
        int neq = (int)eq_cnt; if (neq > 64) neq = 64;
        int need = KSEL - nlt;
        if (need < 0) need = 0;
        if (need > neq) need = neq;
        // ties at T rank by ascending index (jax top_k order): pick 'need' smallest
        for (int a = 0; a < need; ++a) {
            int best = a;
            for (int c = a + 1; c < neq; ++c)
                if (eq_idx[c] < eq_idx[best]) best = c;
            int tmp = eq_idx[a]; eq_idx[a] = eq_idx[best]; eq_idx[best] = tmp;
        }
        int* op = knn_out + (size_t)q * KNN;
        int w = 0;
        if (nlt > 0) {
            // drop global min by (key, idx) -- it lives in the lt set
            int bpos = 0;
            for (int a = 1; a < nlt; ++a)
                if (lt_key[a] < lt_key[bpos] ||
                    (lt_key[a] == lt_key[bpos] && lt_idx[a] < lt_idx[bpos])) bpos = a;
            for (int a = 0; a < nlt; ++a) if (a != bpos && w < KNN) op[w++] = lt_idx[a];
            for (int a = 0; a < need; ++a) if (w < KNN) op[w++] = eq_idx[a];
        } else {
            // all 33 tie at T: drop smallest index
            for (int a = 1; a < need; ++a) if (w < KNN) op[w++] = eq_idx[a];
        }
    }
}

// ---------------- Kernel 2: per-point 3-layer MLP (one scale per block) ------
// grid: (B*N/32, 3), block 256. F layout [B][N][384], channel = s*128+o
__global__ __launch_bounds__(256) void pointmlp_kernel(
    const float* __restrict__ x,
    const float* __restrict__ sW0, const float* __restrict__ sb0,
    const float* __restrict__ sW1, const float* __restrict__ sb1,
    const float* __restrict__ sW2, const float* __restrict__ sb2,
    float* __restrict__ F)
{
    __shared__ __align__(16) float BUF[8192]; // phaseA: W0[0..192)|b0[192..256)|W1t[256..4352)|h0[4352..6656) ; phaseB: W2t[8192]
    __shared__ __align__(16) float h1s[64 * 36];
    __shared__ float b1s[64];
    __shared__ float b2s[128];
    __shared__ float pts[3 * 33];

    const int t = threadIdx.x;
    const int s = blockIdx.y;
    const int tile = blockIdx.x;
    const int b = tile >> 7;
    const int j0 = (tile & 127) << 5;
    const float* xb = x + (size_t)b * 3 * NPTS;

    if (t < 192) BUF[t] = sW0[s * 192 + t];
    else if (t < 256) BUF[t] = sb0[s * 64 + (t - 192)];
    if (t < 64) b1s[t] = sb1[s * 64 + t];
    if (t < 128) b2s[t] = sb2[s * 128 + t];
    if (t < 96) { int c = t >> 5, p = t & 31; pts[c * 33 + p] = xb[c * NPTS + j0 + p]; }
    {
        const float* W1 = sW1 + (size_t)s * 4096;
        int o = t & 63, q = t >> 6;
        #pragma unroll
        for (int r = 0; r < 4; ++r) {
            float4 w = *(const float4*)(W1 + o * 64 + q * 16 + r * 4);
            int i = q * 16 + r * 4;
            BUF[256 + (i + 0) * 64 + o] = w.x;
            BUF[256 + (i + 1) * 64 + o] = w.y;
            BUF[256 + (i + 2) * 64 + o] = w.z;
            BUF[256 + (i + 3) * 64 + o] = w.w;
        }
    }
    __syncthreads();
    const int o = t & 63, pg = t >> 6;
    float* h0 = BUF + 4352;
    {   // layer 1: 3 -> 64
        float w0 = BUF[o * 3], w1 = BUF[o * 3 + 1], w2 = BUF[o * 3 + 2], bb = BUF[192 + o];
        #pragma unroll
        for (int p = 0; p < 8; ++p) {
            int pp = pg * 8 + p;
            float a = bb + w0 * pts[pp] + w1 * pts[33 + pp] + w2 * pts[66 + pp];
            h0[o * 36 + pp] = fmaxf(a, 0.0f);
        }
    }
    __syncthreads();
    {   // layer 2: 64 -> 64
        float acc[8];
        #pragma unroll
        for (int p = 0; p < 8; ++p) acc[p] = b1s[o];
        for (int i = 0; i < 64; ++i) {
            float w = BUF[256 + i * 64 + o];
            float4 ha = *(const float4*)&h0[i * 36 + pg * 8];
            float4 hb = *(const float4*)&h0[i * 36 + pg * 8 + 4];
            acc[0] += w * ha.x; acc[1] += w * ha.y; acc[2] += w * ha.z; acc[3] += w * ha.w;
            acc[4] += w * hb.x; acc[5] += w * hb.y; acc[6] += w * hb.z; acc[7] += w * hb.w;
        }
        #pragma unroll
        for (int p = 0; p < 8; ++p) h1s[o * 36 + pg * 8 + p] = fmaxf(acc[p], 0.0f);
    }
    __syncthreads();
    {   // restage: W2t over the whole BUF (W0/W1t/h0 dead)
        const float* W2 = sW2 + (size_t)s * 8192;
        int o2 = t & 127, q = t >> 7;
        #pragma unroll
        for (int r = 0; r < 8; ++r) {
            float4 w = *(const float4*)(W2 + o2 * 64 + q * 32 + r * 4);
            int i = q * 32 + r * 4;
            BUF[(i + 0) * 128 + o2] = w.x;
            BUF[(i + 1) * 128 + o2] = w.y;
            BUF[(i + 2) * 128 + o2] = w.z;
            BUF[(i + 3) * 128 + o2] = w.w;
        }
    }
    __syncthreads();
    {   // layer 3: 64 -> 128, coalesced F writes (lanes vary o2)
        int o2 = t & 127, ph = t >> 7;
        float acc[16];
        #pragma unroll
        for (int p = 0; p < 16; ++p) acc[p] = b2s[o2];
        for (int i = 0; i < 64; ++i) {
            float w = BUF[i * 128 + o2];
            float4 ha = *(const float4*)&h1s[i * 36 + ph * 16];
            float4 hb = *(const float4*)&h1s[i * 36 + ph * 16 + 4];
            float4 hc = *(const float4*)&h1s[i * 36 + ph * 16 + 8];
            float4 hd = *(const float4*)&h1s[i * 36 + ph * 16 + 12];
            acc[0]  += w * ha.x; acc[1]  += w * ha.y; acc[2]  += w * ha.z; acc[3]  += w * ha.w;
            acc[4]  += w * hb.x; acc[5]  += w * hb.y; acc[6]  += w * hb.z; acc[7]  += w * hb.w;
            acc[8]  += w * hc.x; acc[9]  += w * hc.y; acc[10] += w * hc.z; acc[11] += w * hc.w;
            acc[12] += w * hd.x; acc[13] += w * hd.y; acc[14] += w * hd.z; acc[15] += w * hd.w;
        }
        #pragma unroll
        for (int p = 0; p < 16; ++p) {
            int j = j0 + ph * 16 + p;
            F[((size_t)b * NPTS + j) * 384 + s * 128 + o2] = fmaxf(acc[p], 0.0f);
        }
    }
}

// ---------------- Kernel 3: gather-max over 32 neighbors + transpose ---------
// grid: (B*N/64, 6 channel-chunks), block 256. point layout [B][384][N]
__global__ __launch_bounds__(256) void maxgather_kernel(
    const float* __restrict__ F, const int* __restrict__ knn,
    float* __restrict__ point)
{
    __shared__ int idxS[64 * KNN];
    __shared__ float T[64 * 65];
    const int t = threadIdx.x;
    const int b = blockIdx.x >> 6;
    const int n0 = (blockIdx.x & 63) << 6;
    const int cc = blockIdx.y;

    #pragma unroll
    for (int r = 0; r < 8; ++r) {
        int lin = t + r * 256;
        idxS[lin] = knn[((size_t)b * NPTS + n0) * KNN + lin];
    }
    __syncthreads();
    const int w = t >> 6, lane = t & 63;
    const float* Fb = F + (size_t)b * NPTS * 384 + cc * 64 + lane;
    #pragma unroll
    for (int g = 0; g < 2; ++g) {
        float m[8];
        #pragma unroll
        for (int u = 0; u < 8; ++u) m[u] = 0.0f;   // post-relu features are >= 0
        int nb_ = w * 16 + g * 8;
        for (int k = 0; k < KNN; ++k) {
            #pragma unroll
            for (int u = 0; u < 8; ++u) {
                int j = idxS[(nb_ + u) * KNN + k];
                float v = Fb[(size_t)j * 384];
                m[u] = fmaxf(m[u], v);
            }
        }
        #pragma unroll
        for (int u = 0; u < 8; ++u) T[lane * 65 + nb_ + u] = m[u];
    }
    __syncthreads();
    #pragma unroll
    for (int r = 0; r < 16; ++r) {
        int lin = t + r * 256;
        int c = lin >> 6, nl = lin & 63;
        point[((size_t)b * 384 + cc * 64 + c) * NPTS + n0 + nl] = T[c * 65 + nl];
    }
}

// ---------------- Kernel 4: fp32 GEMM + bias + relu --------------------------
// C[b][M][N] = relu(W[M][K] * Bm[b][K][N] + bias), tiles 128x128x16, micro 8x8
__global__ __launch_bounds__(256) void gemm_kernel(
    const float* __restrict__ W, const float* __restrict__ Bm,
    const float* __restrict__ bias, float* __restrict__ out,
    int M, int K)
{
    __shared__ __align__(16) float At[16 * 132];
    __shared__ __align__(16) float Bt[16 * 132];
    __shared__ float biasS[128];

    const int t = threadIdx.x;
    const int b = blockIdx.z;
    const int m0 = blockIdx.x * 128;
    const int n0 = blockIdx.y * 128;
    const int tx = t & 15, ty = t >> 4;

    if (t < 128) biasS[t] = bias[m0 + t];

    const float* Wp = W + (size_t)(m0 + (t & 127)) * K + ((t >> 7) * 8);
    const float* Bp = Bm + (size_t)b * K * NPTS + n0;
    const int kb1 = t >> 5, nb1 = (t & 31) * 4;
    const int kb2 = kb1 + 8;

    float acc[64];
    #pragma unroll
    for (int i = 0; i < 64; ++i) acc[i] = 0.0f;

    for (int k0 = 0; k0 < K; k0 += 16) {
        float4 a0 = *(const float4*)(Wp + k0);
        float4 a1 = *(const float4*)(Wp + k0 + 4);
        float4 bv0 = *(const float4*)(Bp + (size_t)(k0 + kb1) * NPTS + nb1);
        float4 bv1 = *(const float4*)(Bp + (size_t)(k0 + kb2) * NPTS + nb1);
        __syncthreads();
        {
            int m = t & 127, kq = (t >> 7) * 8;
            At[(kq + 0) * 132 + m] = a0.x;
            At[(kq + 1) * 132 + m] = a0.y;
            At[(kq + 2) * 132 + m] = a0.z;
            At[(kq + 3) * 132 + m] = a0.w;
            At[(kq + 4) * 132 + m] = a1.x;
            At[(kq + 5) * 132 + m] = a1.y;
            At[(kq + 6) * 132 + m] = a1.z;
            At[(kq + 7) * 132 + m] = a1.w;
            *(float4*)&Bt[kb1 * 132 + nb1] = bv0;
            *(float4*)&Bt[kb2 * 132 + nb1] = bv1;
        }
        __syncthreads();
        #pragma unroll
        for (int k = 0; k < 16; ++k) {
            float4 av0 = *(const float4*)&At[k * 132 + ty * 4];
            float4 av1 = *(const float4*)&At[k * 132 + 64 + ty * 4];
            float4 bw0 = *(const float4*)&Bt[k * 132 + tx * 4];
            float4 bw1 = *(const float4*)&Bt[k * 132 + 64 + tx * 4];
            float ar[8] = {av0.x, av0.y, av0.z, av0.w, av1.x, av1.y, av1.z, av1.w};
            float br[8] = {bw0.x, bw0.y, bw0.z, bw0.w, bw1.x, bw1.y, bw1.z, bw1.w};
            #pragma unroll
            for (int r = 0; r < 8; ++r)
                #pragma unroll
                for (int c = 0; c < 8; ++c)
                    acc[r * 8 + c] += ar[r] * br[c];
        }
    }
    #pragma unroll
    for (int rq = 0; rq < 2; ++rq)
    #pragma unroll
    for (int r = 0; r < 4; ++r) {
        int mm = rq * 64 + ty * 4 + r;
        float bs = biasS[mm];
        float* orow = out + ((size_t)b * M + m0 + mm) * NPTS + n0;
        int ra = rq * 4 + r;
        float4 o0, o1;
        o0.x = fmaxf(acc[ra * 8 + 0] + bs, 0.0f);
        o0.y = fmaxf(acc[ra * 8 + 1] + bs, 0.0f);
        o0.z = fmaxf(acc[ra * 8 + 2] + bs, 0.0f);
        o0.w = fmaxf(acc[ra * 8 + 3] + bs, 0.0f);
        o1.x = fmaxf(acc[ra * 8 + 4] + bs, 0.0f);
        o1.y = fmaxf(acc[ra * 8 + 5] + bs, 0.0f);
        o1.z = fmaxf(acc[ra * 8 + 6] + bs, 0.0f);
        o1.w = fmaxf(acc[ra * 8 + 7] + bs, 0.0f);
        *(float4*)(orow + tx * 4) = o0;
        *(float4*)(orow + 64 + tx * 4) = o1;
    }
}

// ---------------- Kernel 5: row max of gf -> global_feature ------------------
__global__ __launch_bounds__(256) void rowmax_kernel(const float* __restrict__ gf,
                                                     float* __restrict__ outv)
{
    const int wid = threadIdx.x >> 6, lane = threadIdx.x & 63;
    const int row = blockIdx.x * 4 + wid;
    const float4* p = (const float4*)(gf + (size_t)row * NPTS);
    float m = 0.0f;   // gf is post-relu, >= 0
    #pragma unroll
    for (int i = 0; i < 16; ++i) {
        float4 v = p[lane + i * 64];
        m = fmaxf(m, fmaxf(fmaxf(v.x, v.y), fmaxf(v.z, v.w)));
    }
    #pragma unroll
    for (int off = 32; off > 0; off >>= 1)
        m = fmaxf(m, __shfl_xor(m, off, 64));
    if (lane == 0) outv[row] = m;
}

extern "C" void kernel_launch(void* const* d_in, const int* in_sizes, int n_in,
                              void* d_out, int out_size, void* d_ws, size_t ws_size,
                              hipStream_t stream)
{
    const float* x   = (const float*)d_in[0];
    const float* sW0 = (const float*)d_in[1];
    const float* sb0 = (const float*)d_in[2];
    const float* sW1 = (const float*)d_in[3];
    const float* sb1 = (const float*)d_in[4];
    const float* sW2 = (const float*)d_in[5];
    const float* sb2 = (const float*)d_in[6];
    const float* gW0 = (const float*)d_in[7];
    const float* gb0 = (const float*)d_in[8];
    const float* gW1 = (const float*)d_in[9];
    const float* gb1 = (const float*)d_in[10];
    const float* mW0 = (const float*)d_in[11];
    const float* mb0 = (const float*)d_in[12];
    const float* mW1 = (const float*)d_in[13];
    const float* mb1 = (const float*)d_in[14];
    float* outp = (float*)d_out;

    char* ws = (char*)d_ws;
    int*   idx   = (int*)(ws);                       // 2 MB
    float* F     = (float*)(ws + 2097152u);          // 25.2 MB  [B][N][384]
    float* point = (float*)(ws + 27262976u);         // 25.2 MB  [B][384][N]
    float* gf0   = (float*)(ws + 52428800u);         // 16.8 MB  [B][256][N]
    float* gf    = (float*)(ws + 69206016u);         // 67.1 MB  [B][1024][N]
    float* msf0  = (float*)(ws + 2097152u);          // aliases F (dead by then)

    hipLaunchKernelGGL(knn_kernel2, dim3(16384), dim3(256), 0, stream, x, idx);
    hipLaunchKernelGGL(pointmlp_kernel, dim3(512, 3), dim3(256), 0, stream,
                       x, sW0, sb0, sW1, sb1, sW2, sb2, F);
    hipLaunchKernelGGL(maxgather_kernel, dim3(256, 6), dim3(256), 0, stream, F, idx, point);
    hipLaunchKernelGGL(gemm_kernel, dim3(2, 32, 4), dim3(256), 0, stream,
                       gW0, point, gb0, gf0, 256, 384);
    hipLaunchKernelGGL(gemm_kernel, dim3(8, 32, 4), dim3(256), 0, stream,
                       gW1, gf0, gb1, gf, 1024, 256);
    hipLaunchKernelGGL(rowmax_kernel, dim3(1024), dim3(256), 0, stream, gf, outp);
    hipLaunchKernelGGL(gemm_kernel, dim3(2, 32, 4), dim3(256), 0, stream,
                       mW0, gf, mb0, msf0, 256, 1024);
    hipLaunchKernelGGL(gemm_kernel, dim3(1, 32, 4), dim3(256), 0, stream,
                       mW1, msf0, mb1, outp + 4096, 128, 256);
}

// Round 3
// 528.670 us; speedup vs baseline: 1.8968x; 1.4018x over previous
//
#include <hip/hip_runtime.h>
#include <hip/hip_bf16.h>

#define NPTS 4096
#define KNN  32

typedef __attribute__((ext_vector_type(8))) short short8;
typedef __attribute__((ext_vector_type(4))) float floatx4;

__device__ __forceinline__ unsigned short f2bf(float f) {
    unsigned u = __float_as_uint(f);
    u = (u + 0x7FFFu + ((u >> 16) & 1u)) >> 16;
    return (unsigned short)u;
}
__device__ __forceinline__ float bf2f(unsigned short v) {
    return __uint_as_float(((unsigned)v) << 16);
}

// ---------------- Kernel 1: exact KNN, early-exit interval search ------------
// grid: B*N = 16384 blocks x 256 thr; 16 candidate keys/thread in registers.
// Invariant: cntLo = #{key < lo} (<33), cntHi = #{key <= hi} (>=33). Stop when
// interval holds <=48 candidates; thread 0 finishes by tiny selection.
__global__ __launch_bounds__(256) void knn_kernel3(const float* __restrict__ x,
                                                   int* __restrict__ knn_out)
{
    __shared__ unsigned sb[2][4];
    __shared__ unsigned lt_key[40]; __shared__ int lt_idx[40];
    __shared__ unsigned md_key[64]; __shared__ int md_idx[64];
    __shared__ unsigned lt_cnt, md_cnt;

    const int t = threadIdx.x;
    const int q = blockIdx.x;
    const int b = q >> 12;
    const int n = q & (NPTS - 1);
    const float* xb = x + (size_t)b * 3 * NPTS;

    const float px = xb[n], py = xb[NPTS + n], pz = xb[2 * NPTS + n];
    const float sqn = px * px + py * py + pz * pz;

    // candidates j = t*16 + r  (contiguous per thread -> float4 loads)
    const float4* xx = (const float4*)(xb + (t << 4));
    const float4* xy = (const float4*)(xb + NPTS + (t << 4));
    const float4* xz = (const float4*)(xb + 2 * NPTS + (t << 4));
    float4 AX[4], AY[4], AZ[4];
    #pragma unroll
    for (int r = 0; r < 4; ++r) { AX[r] = xx[r]; AY[r] = xy[r]; AZ[r] = xz[r]; }

    unsigned key[16];
    #pragma unroll
    for (int r4 = 0; r4 < 4; ++r4) {
        float qx, qy, qz, d; unsigned u;
        qx = AX[r4].x; qy = AY[r4].x; qz = AZ[r4].x;
        d = (sqn + qx*qx + qy*qy + qz*qz) - 2.f*(px*qx + py*qy + pz*qz);
        u = __float_as_uint(d); key[r4*4+0] = (u & 0x80000000u) ? ~u : (u | 0x80000000u);
        qx = AX[r4].y; qy = AY[r4].y; qz = AZ[r4].y;
        d = (sqn + qx*qx + qy*qy + qz*qz) - 2.f*(px*qx + py*qy + pz*qz);
        u = __float_as_uint(d); key[r4*4+1] = (u & 0x80000000u) ? ~u : (u | 0x80000000u);
        qx = AX[r4].z; qy = AY[r4].z; qz = AZ[r4].z;
        d = (sqn + qx*qx + qy*qy + qz*qz) - 2.f*(px*qx + py*qy + pz*qz);
        u = __float_as_uint(d); key[r4*4+2] = (u & 0x80000000u) ? ~u : (u | 0x80000000u);
        qx = AX[r4].w; qy = AY[r4].w; qz = AZ[r4].w;
        d = (sqn + qx*qx + qy*qy + qz*qz) - 2.f*(px*qx + py*qy + pz*qz);
        u = __float_as_uint(d); key[r4*4+3] = (u & 0x80000000u) ? ~u : (u | 0x80000000u);
    }
    if (t == 0) { lt_cnt = 0u; md_cnt = 0u; }

    const int wid = t >> 6, lane = t & 63;
    unsigned lo = 0u, hi = 0xFFFFFFFFu, cntLo = 0u, cntHi = 4096u;
    int parity = 0;
    while (cntHi - cntLo > 48u && lo < hi) {
        unsigned mid = lo + ((hi - lo) >> 1);
        unsigned c = 0;
        #pragma unroll
        for (int r = 0; r < 16; ++r)
            c += (unsigned)__popcll(__ballot(key[r] <= mid));
        if (lane == 0) sb[parity][wid] = c;
        __syncthreads();
        unsigned g = sb[parity][0] + sb[parity][1] + sb[parity][2] + sb[parity][3];
        parity ^= 1;
        if (g >= 33u) { hi = mid; cntHi = g; } else { lo = mid + 1u; cntLo = g; }
    }

    #pragma unroll
    for (int r = 0; r < 16; ++r) {
        int j = (t << 4) + r;
        unsigned k = key[r];
        if (k < lo) {
            unsigned p = atomicAdd(&lt_cnt, 1u);
            if (p < 40u) { lt_key[p] = k; lt_idx[p] = j; }
        } else if (k <= hi) {
            unsigned p = atomicAdd(&md_cnt, 1u);
            if (p < 64u) { md_key[p] = k; md_idx[p] = j; }
        }
    }
    __syncthreads();

    if (t == 0) {
        int nlt = (int)lt_cnt; if (nlt > 40) nlt = 40;   // exact: cntLo <= 32
        int nmd = (int)md_cnt; if (nmd > 64) nmd = 64;
        int need = 33 - nlt;
        if (need < 0) need = 0;
        if (need > nmd) need = nmd;
        // partial selection sort of md by (key, idx) ascending, first `need`
        for (int a = 0; a < need; ++a) {
            int best = a;
            for (int c2 = a + 1; c2 < nmd; ++c2)
                if (md_key[c2] < md_key[best] ||
                    (md_key[c2] == md_key[best] && md_idx[c2] < md_idx[best])) best = c2;
            unsigned tk = md_key[a]; md_key[a] = md_key[best]; md_key[best] = tk;
            int ti = md_idx[a]; md_idx[a] = md_idx[best]; md_idx[best] = ti;
        }
        // global min (self) is smallest (key,idx): in lt if lt nonempty else md[0]
        int bpos = -1;
        for (int a = 0; a < nlt; ++a)
            if (bpos < 0 || lt_key[a] < lt_key[bpos] ||
                (lt_key[a] == lt_key[bpos] && lt_idx[a] < lt_idx[bpos])) bpos = a;
        const bool minInLt = (nlt > 0);
        int* op = knn_out + (size_t)q * KNN;
        int w = 0;
        for (int a = 0; a < nlt; ++a)
            if (!(minInLt && a == bpos) && w < KNN) op[w++] = lt_idx[a];
        for (int a = (minInLt ? 0 : 1); a < need; ++a)
            if (w < KNN) op[w++] = md_idx[a];
    }
}

// ---------------- Kernel 2: per-point 3-layer MLP -> F bf16 [b][n][384] ------
__global__ __launch_bounds__(256) void pointmlp_kernel(
    const float* __restrict__ x,
    const float* __restrict__ sW0, const float* __restrict__ sb0,
    const float* __restrict__ sW1, const float* __restrict__ sb1,
    const float* __restrict__ sW2, const float* __restrict__ sb2,
    unsigned short* __restrict__ F)
{
    __shared__ __align__(16) float BUF[8192];
    __shared__ __align__(16) float h1s[64 * 36];
    __shared__ float b1s[64];
    __shared__ float b2s[128];
    __shared__ float pts[3 * 33];

    const int t = threadIdx.x;
    const int s = blockIdx.y;
    const int tile = blockIdx.x;
    const int b = tile >> 7;
    const int j0 = (tile & 127) << 5;
    const float* xb = x + (size_t)b * 3 * NPTS;

    if (t < 192) BUF[t] = sW0[s * 192 + t];
    else if (t < 256) BUF[t] = sb0[s * 64 + (t - 192)];
    if (t < 64) b1s[t] = sb1[s * 64 + t];
    if (t < 128) b2s[t] = sb2[s * 128 + t];
    if (t < 96) { int c = t >> 5, p = t & 31; pts[c * 33 + p] = xb[c * NPTS + j0 + p]; }
    {
        const float* W1 = sW1 + (size_t)s * 4096;
        int o = t & 63, q = t >> 6;
        #pragma unroll
        for (int r = 0; r < 4; ++r) {
            float4 w = *(const float4*)(W1 + o * 64 + q * 16 + r * 4);
            int i = q * 16 + r * 4;
            BUF[256 + (i + 0) * 64 + o] = w.x;
            BUF[256 + (i + 1) * 64 + o] = w.y;
            BUF[256 + (i + 2) * 64 + o] = w.z;
            BUF[256 + (i + 3) * 64 + o] = w.w;
        }
    }
    __syncthreads();
    const int o = t & 63, pg = t >> 6;
    float* h0 = BUF + 4352;
    {
        float w0 = BUF[o * 3], w1 = BUF[o * 3 + 1], w2 = BUF[o * 3 + 2], bb = BUF[192 + o];
        #pragma unroll
        for (int p = 0; p < 8; ++p) {
            int pp = pg * 8 + p;
            float a = bb + w0 * pts[pp] + w1 * pts[33 + pp] + w2 * pts[66 + pp];
            h0[o * 36 + pp] = fmaxf(a, 0.0f);
        }
    }
    __syncthreads();
    {
        float acc[8];
        #pragma unroll
        for (int p = 0; p < 8; ++p) acc[p] = b1s[o];
        for (int i = 0; i < 64; ++i) {
            float w = BUF[256 + i * 64 + o];
            float4 ha = *(const float4*)&h0[i * 36 + pg * 8];
            float4 hb = *(const float4*)&h0[i * 36 + pg * 8 + 4];
            acc[0] += w * ha.x; acc[1] += w * ha.y; acc[2] += w * ha.z; acc[3] += w * ha.w;
            acc[4] += w * hb.x; acc[5] += w * hb.y; acc[6] += w * hb.z; acc[7] += w * hb.w;
        }
        #pragma unroll
        for (int p = 0; p < 8; ++p) h1s[o * 36 + pg * 8 + p] = fmaxf(acc[p], 0.0f);
    }
    __syncthreads();
    {
        const float* W2 = sW2 + (size_t)s * 8192;
        int o2 = t & 127, q = t >> 7;
        #pragma unroll
        for (int r = 0; r < 8; ++r) {
            float4 w = *(const float4*)(W2 + o2 * 64 + q * 32 + r * 4);
            int i = q * 32 + r * 4;
            BUF[(i + 0) * 128 + o2] = w.x;
            BUF[(i + 1) * 128 + o2] = w.y;
            BUF[(i + 2) * 128 + o2] = w.z;
            BUF[(i + 3) * 128 + o2] = w.w;
        }
    }
    __syncthreads();
    {
        int o2 = t & 127, ph = t >> 7;
        float acc[16];
        #pragma unroll
        for (int p = 0; p < 16; ++p) acc[p] = b2s[o2];
        for (int i = 0; i < 64; ++i) {
            float w = BUF[i * 128 + o2];
            float4 ha = *(const float4*)&h1s[i * 36 + ph * 16];
            float4 hb = *(const float4*)&h1s[i * 36 + ph * 16 + 4];
            float4 hc = *(const float4*)&h1s[i * 36 + ph * 16 + 8];
            float4 hd = *(const float4*)&h1s[i * 36 + ph * 16 + 12];
            acc[0]  += w * ha.x; acc[1]  += w * ha.y; acc[2]  += w * ha.z; acc[3]  += w * ha.w;
            acc[4]  += w * hb.x; acc[5]  += w * hb.y; acc[6]  += w * hb.z; acc[7]  += w * hb.w;
            acc[8]  += w * hc.x; acc[9]  += w * hc.y; acc[10] += w * hc.z; acc[11] += w * hc.w;
            acc[12] += w * hd.x; acc[13] += w * hd.y; acc[14] += w * hd.z; acc[15] += w * hd.w;
        }
        #pragma unroll
        for (int p = 0; p < 16; ++p) {
            int j = j0 + ph * 16 + p;
            F[((size_t)b * NPTS + j) * 384 + s * 128 + o2] = f2bf(fmaxf(acc[p], 0.0f));
        }
    }
}

// ---------------- Kernel 3: gather-max (bf16 in/out), point [b][n][384] ------
// uint16 compare valid: post-relu bf16 (>=0) bit patterns are value-monotone.
__global__ __launch_bounds__(384) void maxgather_bf16(
    const unsigned short* __restrict__ F, const int* __restrict__ knn,
    unsigned short* __restrict__ pt)
{
    __shared__ int idxS[KNN];
    const int q = blockIdx.x;            // b*4096 + n
    const int b = q >> 12;
    const int t = threadIdx.x;           // channel 0..383
    if (t < KNN) idxS[t] = knn[(size_t)q * KNN + t];
    __syncthreads();
    const unsigned short* Fb = F + (size_t)b * NPTS * 384;
    unsigned short m = 0;
    #pragma unroll 8
    for (int k = 0; k < KNN; ++k) {
        unsigned short v = Fb[(size_t)idxS[k] * 384 + t];
        m = (v > m) ? v : m;
    }
    pt[(size_t)q * 384 + t] = m;
}

// ---------------- Kernel 4: bf16 MFMA GEMM + bias + relu ---------------------
// C[b] = relu(W[M][K] (fp32, cvt in staging) * B^T[b][n][K] (bf16) + bias)
// OUT_FP32=0: out bf16 [b][n][M] (transposed, feeds next GEMM)
// OUT_FP32=1: out fp32 [b][m][4096]
template<int OUT_FP32>
__global__ __launch_bounds__(256) void gemm_bf16(
    const float* __restrict__ W, const unsigned short* __restrict__ Bt,
    const float* __restrict__ bias, void* __restrict__ outp,
    int M, int K)
{
    __shared__ __align__(16) unsigned short As[128 * 40]; // [m][k] pad 40
    __shared__ __align__(16) unsigned short Bs[128 * 40]; // [n][k] pad 40
    __shared__ float biasS[128];

    const int t = threadIdx.x;
    const int b = blockIdx.z;
    const int m0 = blockIdx.x * 128;
    const int n0 = blockIdx.y * 128;
    if (t < 128) biasS[t] = bias[m0 + t];

    const int wave = t >> 6, lane = t & 63, quad = lane >> 4, l15 = lane & 15;
    const int wr = wave >> 1, wc = wave & 1;

    const int am = t & 127, akh = t >> 7;            // A: row m, k-half (16)
    const float* Wp = W + (size_t)(m0 + am) * K + akh * 16;
    const int bn = t >> 2, bq = t & 3;               // B: 4 thr per n-row
    const unsigned short* Bp = Bt + ((size_t)b * NPTS + n0) * K;

    floatx4 acc[16];
    #pragma unroll
    for (int i = 0; i < 16; ++i) acc[i] = (floatx4){0.f, 0.f, 0.f, 0.f};

    const int nk = K >> 5;
    for (int kt = 0; kt < nk; ++kt) {
        const int k0 = kt << 5;
        float4 a0 = *(const float4*)(Wp + k0);
        float4 a1 = *(const float4*)(Wp + k0 + 4);
        float4 a2 = *(const float4*)(Wp + k0 + 8);
        float4 a3 = *(const float4*)(Wp + k0 + 12);
        uint4 bv0 = *(const uint4*)(Bp + (size_t)bn * K + k0 + bq * 8);
        uint4 bv1 = *(const uint4*)(Bp + (size_t)(bn + 64) * K + k0 + bq * 8);
        __syncthreads();
        {
            unsigned short aw[16];
            aw[0] = f2bf(a0.x); aw[1] = f2bf(a0.y); aw[2] = f2bf(a0.z); aw[3] = f2bf(a0.w);
            aw[4] = f2bf(a1.x); aw[5] = f2bf(a1.y); aw[6] = f2bf(a1.z); aw[7] = f2bf(a1.w);
            aw[8] = f2bf(a2.x); aw[9] = f2bf(a2.y); aw[10] = f2bf(a2.z); aw[11] = f2bf(a2.w);
            aw[12] = f2bf(a3.x); aw[13] = f2bf(a3.y); aw[14] = f2bf(a3.z); aw[15] = f2bf(a3.w);
            uint4* dst = (uint4*)&As[am * 40 + akh * 16];
            dst[0] = *(const uint4*)&aw[0];
            dst[1] = *(const uint4*)&aw[8];
            *(uint4*)&Bs[bn * 40 + bq * 8] = bv0;
            *(uint4*)&Bs[(bn + 64) * 40 + bq * 8] = bv1;
        }
        __syncthreads();
        short8 af[4], bfv[4];
        #pragma unroll
        for (int i = 0; i < 4; ++i)
            af[i] = *(const short8*)&As[(wr * 64 + i * 16 + l15) * 40 + quad * 8];
        #pragma unroll
        for (int j = 0; j < 4; ++j)
            bfv[j] = *(const short8*)&Bs[(wc * 64 + j * 16 + l15) * 40 + quad * 8];
        #pragma unroll
        for (int i = 0; i < 4; ++i)
            #pragma unroll
            for (int j = 0; j < 4; ++j)
                acc[i * 4 + j] = __builtin_amdgcn_mfma_f32_16x16x32_bf16(
                    af[i], bfv[j], acc[i * 4 + j], 0, 0, 0);
    }

    #pragma unroll
    for (int i = 0; i < 4; ++i) {
        const int mbase = wr * 64 + i * 16 + quad * 4;   // local m for reg r
        #pragma unroll
        for (int j = 0; j < 4; ++j) {
            const int n = n0 + wc * 64 + j * 16 + l15;
            float v0 = fmaxf(acc[i * 4 + j][0] + biasS[mbase + 0], 0.f);
            float v1 = fmaxf(acc[i * 4 + j][1] + biasS[mbase + 1], 0.f);
            float v2 = fmaxf(acc[i * 4 + j][2] + biasS[mbase + 2], 0.f);
            float v3 = fmaxf(acc[i * 4 + j][3] + biasS[mbase + 3], 0.f);
            if (OUT_FP32) {
                float* o = (float*)outp + ((size_t)b * M + m0 + mbase) * NPTS + n;
                o[0 * NPTS] = v0; o[1 * NPTS] = v1; o[2 * NPTS] = v2; o[3 * NPTS] = v3;
            } else {
                ushort4 pk;
                pk.x = f2bf(v0); pk.y = f2bf(v1); pk.z = f2bf(v2); pk.w = f2bf(v3);
                *(ushort4*)((unsigned short*)outp +
                            ((size_t)b * NPTS + n) * M + m0 + mbase) = pk;
            }
        }
    }
}

// ---------------- Kernel 5: column max of gft [b][n][1024] -> gfeat ---------
// atomicMax on float bits (valid: values >= 0; poison 0xAA.. is negative int)
__global__ __launch_bounds__(256) void rowmax_bf16(const unsigned short* __restrict__ gft,
                                                   float* __restrict__ outv)
{
    const int b = blockIdx.x >> 4, chunk = blockIdx.x & 15;
    const int t = threadIdx.x;
    const ushort4* base = (const ushort4*)(gft + ((size_t)b * NPTS + chunk * 256) * 1024);
    float m0 = 0.f, m1 = 0.f, m2 = 0.f, m3 = 0.f;
    for (int n = 0; n < 256; ++n) {
        ushort4 v = base[(size_t)n * 256 + t];
        m0 = fmaxf(m0, bf2f(v.x));
        m1 = fmaxf(m1, bf2f(v.y));
        m2 = fmaxf(m2, bf2f(v.z));
        m3 = fmaxf(m3, bf2f(v.w));
    }
    int* o = (int*)&outv[(size_t)b * 1024 + t * 4];
    atomicMax(o + 0, __float_as_int(m0));
    atomicMax(o + 1, __float_as_int(m1));
    atomicMax(o + 2, __float_as_int(m2));
    atomicMax(o + 3, __float_as_int(m3));
}

extern "C" void kernel_launch(void* const* d_in, const int* in_sizes, int n_in,
                              void* d_out, int out_size, void* d_ws, size_t ws_size,
                              hipStream_t stream)
{
    const float* x   = (const float*)d_in[0];
    const float* sW0 = (const float*)d_in[1];
    const float* sb0 = (const float*)d_in[2];
    const float* sW1 = (const float*)d_in[3];
    const float* sb1 = (const float*)d_in[4];
    const float* sW2 = (const float*)d_in[5];
    const float* sb2 = (const float*)d_in[6];
    const float* gW0 = (const float*)d_in[7];
    const float* gb0 = (const float*)d_in[8];
    const float* gW1 = (const float*)d_in[9];
    const float* gb1 = (const float*)d_in[10];
    const float* mW0 = (const float*)d_in[11];
    const float* mb0 = (const float*)d_in[12];
    const float* mW1 = (const float*)d_in[13];
    const float* mb1 = (const float*)d_in[14];
    float* outp = (float*)d_out;

    char* ws = (char*)d_ws;
    int*            idx     = (int*)(ws);                        // 2 MB
    unsigned short* F       = (unsigned short*)(ws + 2097152u);  // 12.6 MB  [b][n][384] bf16
    unsigned short* point_t = (unsigned short*)(ws + 16777216u); // 12.6 MB  [b][n][384] bf16
    unsigned short* gf0t    = (unsigned short*)(ws + 33554432u); // 8.4 MB   [b][n][256] bf16
    unsigned short* gft     = (unsigned short*)(ws + 50331648u); // 33.6 MB  [b][n][1024] bf16
    unsigned short* msf0t   = (unsigned short*)(ws + 100663296u);// 8.4 MB   [b][n][256] bf16

    knn_kernel3<<<dim3(16384), dim3(256), 0, stream>>>(x, idx);
    pointmlp_kernel<<<dim3(512, 3), dim3(256), 0, stream>>>(
        x, sW0, sb0, sW1, sb1, sW2, sb2, F);
    maxgather_bf16<<<dim3(16384), dim3(384), 0, stream>>>(F, idx, point_t);
    gemm_bf16<0><<<dim3(2, 32, 4), dim3(256), 0, stream>>>(gW0, point_t, gb0, gf0t, 256, 384);
    gemm_bf16<0><<<dim3(8, 32, 4), dim3(256), 0, stream>>>(gW1, gf0t, gb1, gft, 1024, 256);
    rowmax_bf16<<<dim3(64), dim3(256), 0, stream>>>(gft, outp);
    gemm_bf16<0><<<dim3(2, 32, 4), dim3(256), 0, stream>>>(mW0, gft, mb0, msf0t, 256, 1024);
    gemm_bf16<1><<<dim3(1, 32, 4), dim3(256), 0, stream>>>(mW1, msf0t, mb1, outp + 4096, 128, 256);
}

// Round 5
// 527.181 us; speedup vs baseline: 1.9022x; 1.0028x over previous
//
#include <hip/hip_runtime.h>
#include <hip/hip_bf16.h>

#define NPTS 4096
#define KNN  32

typedef __attribute__((ext_vector_type(8))) short short8;
typedef __attribute__((ext_vector_type(4))) float floatx4;

__device__ __forceinline__ unsigned short f2bf(float f) {
    unsigned u = __float_as_uint(f);
    u = (u + 0x7FFFu + ((u >> 16) & 1u)) >> 16;
    return (unsigned short)u;
}
__device__ __forceinline__ float bf2f(unsigned short v) {
    return __uint_as_float(((unsigned)v) << 16);
}

// ---------------- Kernel 0: pack points as (x,y,z,|p|^2) ---------------------
__global__ __launch_bounds__(256) void prep_pts(const float* __restrict__ x,
                                                float4* __restrict__ pts4)
{
    const int i = blockIdx.x * 256 + threadIdx.x;   // 0..16383 = b*4096+n
    const int b = i >> 12, n = i & (NPTS - 1);
    const float* xb = x + (size_t)b * 3 * NPTS;
    const float qx = xb[n], qy = xb[NPTS + n], qz = xb[2 * NPTS + n];
    pts4[i] = make_float4(qx, qy, qz, qx * qx + qy * qy + qz * qz);
}

// ---------------- Kernel 1: exact KNN, one wave per query --------------------
// 64 candidate keys/lane in VGPRs. Wave-local ballot binary search until the
// candidate set {key <= hi} has <= 64 elements (count cntHi >= 33 invariant),
// then parallel exact ranking of that set; winners = global ranks 1..32 by
// (key, idx) lexicographic (matches jax top_k incl. tie order; rank 0 = self).
__global__ __launch_bounds__(256) void knn_kernel4(const float4* __restrict__ pts4,
                                                   int* __restrict__ knn_out)
{
    __shared__ unsigned long long C[4][80];
    __shared__ unsigned cnt[4];

    const int t = threadIdx.x, w = t >> 6, lane = t & 63;
    const int q = blockIdx.x * 4 + w;
    const int b = q >> 12, n = q & (NPTS - 1);
    const float4* P = pts4 + ((size_t)b << 12);

    const float4 s = P[n];                       // broadcast load
    const float px = s.x, py = s.y, pz = s.z, sqn = s.w;

    unsigned key[64];
    #pragma unroll
    for (int rc = 0; rc < 8; ++rc) {
        float4 cc[8];
        #pragma unroll
        for (int u = 0; u < 8; ++u) cc[u] = P[((rc * 8 + u) << 6) + lane];
        #pragma unroll
        for (int u = 0; u < 8; ++u) {
            float d = (sqn + cc[u].w) -
                      2.0f * (px * cc[u].x + py * cc[u].y + pz * cc[u].z);
            unsigned uu = __float_as_uint(d);
            key[rc * 8 + u] = (uu & 0x80000000u) ? ~uu : (uu | 0x80000000u);
        }
    }
    if (lane == 0) cnt[w] = 0u;

    // wave-uniform binary search (ballot results are uniform across the wave)
    unsigned lo = 0u, hi = 0xFFFFFFFFu, cntHi = 4096u;
    while (cntHi > 64u && lo < hi) {
        unsigned mid = lo + ((hi - lo) >> 1);
        unsigned c = 0;
        #pragma unroll
        for (int r = 0; r < 64; ++r)
            c += (unsigned)__popcll(__ballot(key[r] <= mid));
        if (c >= 33u) { hi = mid; cntHi = c; } else { lo = mid + 1u; }
    }

    // collect candidate set {key <= hi} (size == cntHi, 33..64 normally)
    #pragma unroll
    for (int r = 0; r < 64; ++r) {
        if (key[r] <= hi) {
            unsigned p = atomicAdd(&cnt[w], 1u);
            if (p < 80u)
                C[w][p] = ((unsigned long long)key[r] << 32) |
                          (unsigned)((r << 6) + lane);
        }
    }
    __syncthreads();   // defensive LDS visibility fence (1 barrier per block)
    int nc = (int)cnt[w]; if (nc > 80) nc = 80;
    int* op = knn_out + (size_t)q * KNN;
    if (lane < nc) {
        unsigned long long me = C[w][lane];
        int rank = 0;
        for (int j = 0; j < nc; ++j) rank += (C[w][j] < me) ? 1 : 0;
        if (rank >= 1 && rank <= KNN) op[rank - 1] = (int)(me & 0xFFFFFFFFull);
    }
    if (nc > 64 && lane < nc - 64) {   // pathological mass-tie overflow path
        unsigned long long me = C[w][64 + lane];
        int rank = 0;
        for (int j = 0; j < nc; ++j) rank += (C[w][j] < me) ? 1 : 0;
        if (rank >= 1 && rank <= KNN) op[rank - 1] = (int)(me & 0xFFFFFFFFull);
    }
}

// ---------------- Kernel 2: per-point 3-layer MLP -> F bf16 [b][n][384] ------
__global__ __launch_bounds__(256) void pointmlp_kernel(
    const float* __restrict__ x,
    const float* __restrict__ sW0, const float* __restrict__ sb0,
    const float* __restrict__ sW1, const float* __restrict__ sb1,
    const float* __restrict__ sW2, const float* __restrict__ sb2,
    unsigned short* __restrict__ F)
{
    __shared__ __align__(16) float BUF[8192];
    __shared__ __align__(16) float h1s[64 * 36];
    __shared__ float b1s[64];
    __shared__ float b2s[128];
    __shared__ float pts[3 * 33];

    const int t = threadIdx.x;
    const int s = blockIdx.y;
    const int tile = blockIdx.x;
    const int b = tile >> 7;
    const int j0 = (tile & 127) << 5;
    const float* xb = x + (size_t)b * 3 * NPTS;

    if (t < 192) BUF[t] = sW0[s * 192 + t];
    else if (t < 256) BUF[t] = sb0[s * 64 + (t - 192)];
    if (t < 64) b1s[t] = sb1[s * 64 + t];
    if (t < 128) b2s[t] = sb2[s * 128 + t];
    if (t < 96) { int c = t >> 5, p = t & 31; pts[c * 33 + p] = xb[c * NPTS + j0 + p]; }
    {
        const float* W1 = sW1 + (size_t)s * 4096;
        int o = t & 63, q = t >> 6;
        #pragma unroll
        for (int r = 0; r < 4; ++r) {
            float4 w = *(const float4*)(W1 + o * 64 + q * 16 + r * 4);
            int i = q * 16 + r * 4;
            BUF[256 + (i + 0) * 64 + o] = w.x;
            BUF[256 + (i + 1) * 64 + o] = w.y;
            BUF[256 + (i + 2) * 64 + o] = w.z;
            BUF[256 + (i + 3) * 64 + o] = w.w;
        }
    }
    __syncthreads();
    const int o = t & 63, pg = t >> 6;
    float* h0 = BUF + 4352;
    {
        float w0 = BUF[o * 3], w1 = BUF[o * 3 + 1], w2 = BUF[o * 3 + 2], bb = BUF[192 + o];
        #pragma unroll
        for (int p = 0; p < 8; ++p) {
            int pp = pg * 8 + p;
            float a = bb + w0 * pts[pp] + w1 * pts[33 + pp] + w2 * pts[66 + pp];
            h0[o * 36 + pp] = fmaxf(a, 0.0f);
        }
    }
    __syncthreads();
    {
        float acc[8];
        #pragma unroll
        for (int p = 0; p < 8; ++p) acc[p] = b1s[o];
        for (int i = 0; i < 64; ++i) {
            float w = BUF[256 + i * 64 + o];
            float4 ha = *(const float4*)&h0[i * 36 + pg * 8];
            float4 hb = *(const float4*)&h0[i * 36 + pg * 8 + 4];
            acc[0] += w * ha.x; acc[1] += w * ha.y; acc[2] += w * ha.z; acc[3] += w * ha.w;
            acc[4] += w * hb.x; acc[5] += w * hb.y; acc[6] += w * hb.z; acc[7] += w * hb.w;
        }
        #pragma unroll
        for (int p = 0; p < 8; ++p) h1s[o * 36 + pg * 8 + p] = fmaxf(acc[p], 0.0f);
    }
    __syncthreads();
    {
        const float* W2 = sW2 + (size_t)s * 8192;
        int o2 = t & 127, q = t >> 7;
        #pragma unroll
        for (int r = 0; r < 8; ++r) {
            float4 w = *(const float4*)(W2 + o2 * 64 + q * 32 + r * 4);
            int i = q * 32 + r * 4;
            BUF[(i + 0) * 128 + o2] = w.x;
            BUF[(i + 1) * 128 + o2] = w.y;
            BUF[(i + 2) * 128 + o2] = w.z;
            BUF[(i + 3) * 128 + o2] = w.w;
        }
    }
    __syncthreads();
    {
        int o2 = t & 127, ph = t >> 7;
        float acc[16];
        #pragma unroll
        for (int p = 0; p < 16; ++p) acc[p] = b2s[o2];
        for (int i = 0; i < 64; ++i) {
            float w = BUF[i * 128 + o2];
            float4 ha = *(const float4*)&h1s[i * 36 + ph * 16];
            float4 hb = *(const float4*)&h1s[i * 36 + ph * 16 + 4];
            float4 hc = *(const float4*)&h1s[i * 36 + ph * 16 + 8];
            float4 hd = *(const float4*)&h1s[i * 36 + ph * 16 + 12];
            acc[0]  += w * ha.x; acc[1]  += w * ha.y; acc[2]  += w * ha.z; acc[3]  += w * ha.w;
            acc[4]  += w * hb.x; acc[5]  += w * hb.y; acc[6]  += w * hb.z; acc[7]  += w * hb.w;
            acc[8]  += w * hc.x; acc[9]  += w * hc.y; acc[10] += w * hc.z; acc[11] += w * hc.w;
            acc[12] += w * hd.x; acc[13] += w * hd.y; acc[14] += w * hd.z; acc[15] += w * hd.w;
        }
        #pragma unroll
        for (int p = 0; p < 16; ++p) {
            int j = j0 + ph * 16 + p;
            F[((size_t)b * NPTS + j) * 384 + s * 128 + o2] = f2bf(fmaxf(acc[p], 0.0f));
        }
    }
}

// ---------------- Kernel 3: gather-max (bf16 in/out), point [b][n][384] ------
// uint16 compare valid: post-relu bf16 (>=0) bit patterns are value-monotone.
__global__ __launch_bounds__(384) void maxgather_bf16(
    const unsigned short* __restrict__ F, const int* __restrict__ knn,
    unsigned short* __restrict__ pt)
{
    __shared__ int idxS[KNN];
    const int q = blockIdx.x;            // b*4096 + n
    const int b = q >> 12;
    const int t = threadIdx.x;           // channel 0..383
    if (t < KNN) idxS[t] = knn[(size_t)q * KNN + t];
    __syncthreads();
    const unsigned short* Fb = F + (size_t)b * NPTS * 384;
    unsigned short m = 0;
    #pragma unroll 8
    for (int k = 0; k < KNN; ++k) {
        unsigned short v = Fb[(size_t)idxS[k] * 384 + t];
        m = (v > m) ? v : m;
    }
    pt[(size_t)q * 384 + t] = m;
}

// ---------------- Kernel 4: bf16 MFMA GEMM + bias + relu ---------------------
// C[b] = relu(W[M][K] (fp32, cvt in staging) * B^T[b][n][K] (bf16) + bias)
// OUT_FP32=0: out bf16 [b][n][M] (transposed, feeds next GEMM)
// OUT_FP32=1: out fp32 [b][m][4096]
template<int OUT_FP32>
__global__ __launch_bounds__(256) void gemm_bf16(
    const float* __restrict__ W, const unsigned short* __restrict__ Bt,
    const float* __restrict__ bias, void* __restrict__ outp,
    int M, int K)
{
    __shared__ __align__(16) unsigned short As[128 * 40]; // [m][k] pad 40
    __shared__ __align__(16) unsigned short Bs[128 * 40]; // [n][k] pad 40
    __shared__ float biasS[128];

    const int t = threadIdx.x;
    const int b = blockIdx.z;
    const int m0 = blockIdx.x * 128;
    const int n0 = blockIdx.y * 128;
    if (t < 128) biasS[t] = bias[m0 + t];

    const int wave = t >> 6, lane = t & 63, quad = lane >> 4, l15 = lane & 15;
    const int wr = wave >> 1, wc = wave & 1;

    const int am = t & 127, akh = t >> 7;            // A: row m, k-half (16)
    const float* Wp = W + (size_t)(m0 + am) * K + akh * 16;
    const int bn = t >> 2, bq = t & 3;               // B: 4 thr per n-row
    const unsigned short* Bp = Bt + ((size_t)b * NPTS + n0) * K;

    floatx4 acc[16];
    #pragma unroll
    for (int i = 0; i < 16; ++i) acc[i] = (floatx4){0.f, 0.f, 0.f, 0.f};

    const int nk = K >> 5;
    for (int kt = 0; kt < nk; ++kt) {
        const int k0 = kt << 5;
        float4 a0 = *(const float4*)(Wp + k0);
        float4 a1 = *(const float4*)(Wp + k0 + 4);
        float4 a2 = *(const float4*)(Wp + k0 + 8);
        float4 a3 = *(const float4*)(Wp + k0 + 12);
        uint4 bv0 = *(const uint4*)(Bp + (size_t)bn * K + k0 + bq * 8);
        uint4 bv1 = *(const uint4*)(Bp + (size_t)(bn + 64) * K + k0 + bq * 8);
        __syncthreads();
        {
            unsigned short aw[16];
            aw[0] = f2bf(a0.x); aw[1] = f2bf(a0.y); aw[2] = f2bf(a0.z); aw[3] = f2bf(a0.w);
            aw[4] = f2bf(a1.x); aw[5] = f2bf(a1.y); aw[6] = f2bf(a1.z); aw[7] = f2bf(a1.w);
            aw[8] = f2bf(a2.x); aw[9] = f2bf(a2.y); aw[10] = f2bf(a2.z); aw[11] = f2bf(a2.w);
            aw[12] = f2bf(a3.x); aw[13] = f2bf(a3.y); aw[14] = f2bf(a3.z); aw[15] = f2bf(a3.w);
            uint4* dst = (uint4*)&As[am * 40 + akh * 16];
            dst[0] = *(const uint4*)&aw[0];
            dst[1] = *(const uint4*)&aw[8];
            *(uint4*)&Bs[bn * 40 + bq * 8] = bv0;
            *(uint4*)&Bs[(bn + 64) * 40 + bq * 8] = bv1;
        }
        __syncthreads();
        short8 af[4], bfv[4];
        #pragma unroll
        for (int i = 0; i < 4; ++i)
            af[i] = *(const short8*)&As[(wr * 64 + i * 16 + l15) * 40 + quad * 8];
        #pragma unroll
        for (int j = 0; j < 4; ++j)
            bfv[j] = *(const short8*)&Bs[(wc * 64 + j * 16 + l15) * 40 + quad * 8];
        #pragma unroll
        for (int i = 0; i < 4; ++i)
            #pragma unroll
            for (int j = 0; j < 4; ++j)
                acc[i * 4 + j] = __builtin_amdgcn_mfma_f32_16x16x32_bf16(
                    af[i], bfv[j], acc[i * 4 + j], 0, 0, 0);
    }

    #pragma unroll
    for (int i = 0; i < 4; ++i) {
        const int mbase = wr * 64 + i * 16 + quad * 4;   // local m for reg r
        #pragma unroll
        for (int j = 0; j < 4; ++j) {
            const int n = n0 + wc * 64 + j * 16 + l15;
            float v0 = fmaxf(acc[i * 4 + j][0] + biasS[mbase + 0], 0.f);
            float v1 = fmaxf(acc[i * 4 + j][1] + biasS[mbase + 1], 0.f);
            float v2 = fmaxf(acc[i * 4 + j][2] + biasS[mbase + 2], 0.f);
            float v3 = fmaxf(acc[i * 4 + j][3] + biasS[mbase + 3], 0.f);
            if (OUT_FP32) {
                float* o = (float*)outp + ((size_t)b * M + m0 + mbase) * NPTS + n;
                o[0 * NPTS] = v0; o[1 * NPTS] = v1; o[2 * NPTS] = v2; o[3 * NPTS] = v3;
            } else {
                ushort4 pk;
                pk.x = f2bf(v0); pk.y = f2bf(v1); pk.z = f2bf(v2); pk.w = f2bf(v3);
                *(ushort4*)((unsigned short*)outp +
                            ((size_t)b * NPTS + n) * M + m0 + mbase) = pk;
            }
        }
    }
}

// ---------------- Kernel 5: column max of gft [b][n][1024] -> gfeat ---------
// atomicMax on float bits (valid: values >= 0; poison 0xAA.. is negative int)
__global__ __launch_bounds__(256) void rowmax_bf16(const unsigned short* __restrict__ gft,
                                                   float* __restrict__ outv)
{
    const int b = blockIdx.x >> 4, chunk = blockIdx.x & 15;
    const int t = threadIdx.x;
    const ushort4* base = (const ushort4*)(gft + ((size_t)b * NPTS + chunk * 256) * 1024);
    float m0 = 0.f, m1 = 0.f, m2 = 0.f, m3 = 0.f;
    for (int n = 0; n < 256; ++n) {
        ushort4 v = base[(size_t)n * 256 + t];
        m0 = fmaxf(m0, bf2f(v.x));
        m1 = fmaxf(m1, bf2f(v.y));
        m2 = fmaxf(m2, bf2f(v.z));
        m3 = fmaxf(m3, bf2f(v.w));
    }
    int* o = (int*)&outv[(size_t)b * 1024 + t * 4];
    atomicMax(o + 0, __float_as_int(m0));
    atomicMax(o + 1, __float_as_int(m1));
    atomicMax(o + 2, __float_as_int(m2));
    atomicMax(o + 3, __float_as_int(m3));
}

extern "C" void kernel_launch(void* const* d_in, const int* in_sizes, int n_in,
                              void* d_out, int out_size, void* d_ws, size_t ws_size,
                              hipStream_t stream)
{
    const float* x   = (const float*)d_in[0];
    const float* sW0 = (const float*)d_in[1];
    const float* sb0 = (const float*)d_in[2];
    const float* sW1 = (const float*)d_in[3];
    const float* sb1 = (const float*)d_in[4];
    const float* sW2 = (const float*)d_in[5];
    const float* sb2 = (const float*)d_in[6];
    const float* gW0 = (const float*)d_in[7];
    const float* gb0 = (const float*)d_in[8];
    const float* gW1 = (const float*)d_in[9];
    const float* gb1 = (const float*)d_in[10];
    const float* mW0 = (const float*)d_in[11];
    const float* mb0 = (const float*)d_in[12];
    const float* mW1 = (const float*)d_in[13];
    const float* mb1 = (const float*)d_in[14];
    float* outp = (float*)d_out;

    char* ws = (char*)d_ws;
    int*            idx     = (int*)(ws);                        // 2 MB
    float4*         pts4    = (float4*)(ws + 2097152u);          // 256 KB
    unsigned short* F       = (unsigned short*)(ws + 4194304u);  // 12.6 MB [b][n][384] bf16
    unsigned short* point_t = (unsigned short*)(ws + 18874368u); // 12.6 MB [b][n][384] bf16
    unsigned short* gf0t    = (unsigned short*)(ws + 33554432u); // 8.4 MB  [b][n][256] bf16
    unsigned short* gft     = (unsigned short*)(ws + 50331648u); // 33.6 MB [b][n][1024] bf16
    unsigned short* msf0t   = (unsigned short*)(ws + 100663296u);// 8.4 MB  [b][n][256] bf16

    prep_pts<<<dim3(64), dim3(256), 0, stream>>>(x, pts4);
    knn_kernel4<<<dim3(4096), dim3(256), 0, stream>>>(pts4, idx);
    pointmlp_kernel<<<dim3(512, 3), dim3(256), 0, stream>>>(
        x, sW0, sb0, sW1, sb1, sW2, sb2, F);
    maxgather_bf16<<<dim3(16384), dim3(384), 0, stream>>>(F, idx, point_t);
    gemm_bf16<0><<<dim3(2, 32, 4), dim3(256), 0, stream>>>(gW0, point_t, gb0, gf0t, 256, 384);
    gemm_bf16<0><<<dim3(8, 32, 4), dim3(256), 0, stream>>>(gW1, gf0t, gb1, gft, 1024, 256);
    rowmax_bf16<<<dim3(64), dim3(256), 0, stream>>>(gft, outp);
    gemm_bf16<0><<<dim3(2, 32, 4), dim3(256), 0, stream>>>(mW0, gft, mb0, msf0t, 256, 1024);
    gemm_bf16<1><<<dim3(1, 32, 4), dim3(256), 0, stream>>>(mW1, msf0t, mb1, outp + 4096, 128, 256);
}

// Round 8
// 368.937 us; speedup vs baseline: 2.7180x; 1.4289x over previous
//
#include <hip/hip_runtime.h>
#include <hip/hip_bf16.h>

#define NPTS 4096
#define KNN  32

typedef __attribute__((ext_vector_type(8))) short short8;
typedef __attribute__((ext_vector_type(4))) float floatx4;

__device__ __forceinline__ unsigned short f2bf(float f) {
    unsigned u = __float_as_uint(f);
    u = (u + 0x7FFFu + ((u >> 16) & 1u)) >> 16;
    return (unsigned short)u;
}
__device__ __forceinline__ float bf2f(unsigned short v) {
    return __uint_as_float(((unsigned)v) << 16);
}

// ---------------- Kernel 0: pack points as (x,y,z,|p|^2) ---------------------
__global__ __launch_bounds__(256) void prep_pts(const float* __restrict__ x,
                                                float4* __restrict__ pts4)
{
    const int i = blockIdx.x * 256 + threadIdx.x;   // 0..16383 = b*4096+n
    const int b = i >> 12, n = i & (NPTS - 1);
    const float* xb = x + (size_t)b * 3 * NPTS;
    const float qx = xb[n], qy = xb[NPTS + n], qz = xb[2 * NPTS + n];
    pts4[i] = make_float4(qx, qy, qz, qx * qx + qy * qy + qz * qz);
}

// ---------------- Kernel 1: exact KNN, block per query -----------------------
// 16 keys/thread in registers (~56 VGPR -> high occupancy). Fixed 15-iteration
// binary search (ROLLED loop - same control shape as the R2-passing kernel) on
// the top-16 key bits over [0x8000, 0xFF7F] (width 0x7F80 = 32640 <= 2^15 ->
// width 1 after 15 halvings; covers ALL finite distances). Lower bound valid:
// #{key < 0x8000_0000} < 33 (only fp-rounding-negative distances = self).
// Collected set {key <= (V<<16)|0xFFFF} is a superset of the top-33; exact
// (key,idx) ranking of it in parallel; ranks 1..32 emitted (rank 0 = self
// dropped). Matches jax top_k incl. tie order.
__global__ __launch_bounds__(256) void knn_kernel7(const float4* __restrict__ pts4,
                                                   int* __restrict__ knn_out)
{
    __shared__ unsigned sred[2][4];
    __shared__ unsigned long long C[96];
    __shared__ unsigned ccnt;

    const int t = threadIdx.x, wid = t >> 6, lane = t & 63;
    const int q = blockIdx.x, b = q >> 12, n = q & (NPTS - 1);
    const float4* P = pts4 + ((size_t)b << 12);
    const float4 s = P[n];
    const float px = s.x, py = s.y, pz = s.z, sqn = s.w;

    if (t == 0) ccnt = 0u;

    // candidates j = (r<<8) + t  -> perfectly coalesced 1KB/instruction
    unsigned key[16];
    #pragma unroll
    for (int g = 0; g < 4; ++g) {
        float4 c0 = P[((g * 4 + 0) << 8) + t];
        float4 c1 = P[((g * 4 + 1) << 8) + t];
        float4 c2 = P[((g * 4 + 2) << 8) + t];
        float4 c3 = P[((g * 4 + 3) << 8) + t];
        float d0 = (sqn + c0.w) - 2.0f * (px * c0.x + py * c0.y + pz * c0.z);
        float d1 = (sqn + c1.w) - 2.0f * (px * c1.x + py * c1.y + pz * c1.z);
        float d2 = (sqn + c2.w) - 2.0f * (px * c2.x + py * c2.y + pz * c2.z);
        float d3 = (sqn + c3.w) - 2.0f * (px * c3.x + py * c3.y + pz * c3.z);
        unsigned u0 = __float_as_uint(d0), u1 = __float_as_uint(d1);
        unsigned u2 = __float_as_uint(d2), u3 = __float_as_uint(d3);
        key[g * 4 + 0] = (u0 & 0x80000000u) ? ~u0 : (u0 | 0x80000000u);
        key[g * 4 + 1] = (u1 & 0x80000000u) ? ~u1 : (u1 | 0x80000000u);
        key[g * 4 + 2] = (u2 & 0x80000000u) ? ~u2 : (u2 | 0x80000000u);
        key[g * 4 + 3] = (u3 & 0x80000000u) ? ~u3 : (u3 | 0x80000000u);
    }

    // fixed 15-iteration search on 16-bit prefix; rolled loop, 1 barrier/iter
    unsigned lo = 0x8000u, hi = 0xFF7Fu;
    for (int it = 0; it < 15; ++it) {
        const unsigned mid = (lo + hi) >> 1;
        const unsigned thr = (mid << 16) | 0xFFFFu;
        unsigned c = 0;
        #pragma unroll
        for (int r = 0; r < 16; ++r)
            c += (unsigned)__popcll(__ballot(key[r] <= thr));
        if (lane == 0) sred[it & 1][wid] = c;
        __syncthreads();
        const unsigned g = sred[it & 1][0] + sred[it & 1][1] +
                           sred[it & 1][2] + sred[it & 1][3];
        if (g >= 33u) hi = mid; else lo = mid + 1u;
    }
    const unsigned thrF = (lo << 16) | 0xFFFFu;   // lo == hi == V

    // collect all candidates <= thrF (count in [33, ~36] for real data)
    #pragma unroll
    for (int r = 0; r < 16; ++r) {
        if (key[r] <= thrF) {
            unsigned p = atomicAdd(&ccnt, 1u);
            if (p < 96u)
                C[p] = ((unsigned long long)key[r] << 32) |
                       (unsigned)((r << 8) + t);
        }
    }
    __syncthreads();

    // parallel exact ranking; winners = ranks 1..32
    int nc = (int)ccnt; if (nc > 96) nc = 96;
    if (t < nc) {
        const unsigned long long me = C[t];
        int rank = 0;
        for (int j = 0; j < nc; ++j) rank += (C[j] < me) ? 1 : 0;
        if (rank >= 1 && rank <= KNN)
            knn_out[(size_t)q * KNN + (rank - 1)] = (int)(me & 0xFFFFFFFFu);
    }
}

// ---------------- Kernel 2: per-point 3-layer MLP -> F bf16 [b][n][384] ------
__global__ __launch_bounds__(256) void pointmlp_kernel(
    const float* __restrict__ x,
    const float* __restrict__ sW0, const float* __restrict__ sb0,
    const float* __restrict__ sW1, const float* __restrict__ sb1,
    const float* __restrict__ sW2, const float* __restrict__ sb2,
    unsigned short* __restrict__ F)
{
    __shared__ __align__(16) float BUF[8192];
    __shared__ __align__(16) float h1s[64 * 36];
    __shared__ float b1s[64];
    __shared__ float b2s[128];
    __shared__ float pts[3 * 33];

    const int t = threadIdx.x;
    const int s = blockIdx.y;
    const int tile = blockIdx.x;
    const int b = tile >> 7;
    const int j0 = (tile & 127) << 5;
    const float* xb = x + (size_t)b * 3 * NPTS;

    if (t < 192) BUF[t] = sW0[s * 192 + t];
    else if (t < 256) BUF[t] = sb0[s * 64 + (t - 192)];
    if (t < 64) b1s[t] = sb1[s * 64 + t];
    if (t < 128) b2s[t] = sb2[s * 128 + t];
    if (t < 96) { int c = t >> 5, p = t & 31; pts[c * 33 + p] = xb[c * NPTS + j0 + p]; }
    {
        const float* W1 = sW1 + (size_t)s * 4096;
        int o = t & 63, q = t >> 6;
        #pragma unroll
        for (int r = 0; r < 4; ++r) {
            float4 w = *(const float4*)(W1 + o * 64 + q * 16 + r * 4);
            int i = q * 16 + r * 4;
            BUF[256 + (i + 0) * 64 + o] = w.x;
            BUF[256 + (i + 1) * 64 + o] = w.y;
            BUF[256 + (i + 2) * 64 + o] = w.z;
            BUF[256 + (i + 3) * 64 + o] = w.w;
        }
    }
    __syncthreads();
    const int o = t & 63, pg = t >> 6;
    float* h0 = BUF + 4352;
    {
        float w0 = BUF[o * 3], w1 = BUF[o * 3 + 1], w2 = BUF[o * 3 + 2], bb = BUF[192 + o];
        #pragma unroll
        for (int p = 0; p < 8; ++p) {
            int pp = pg * 8 + p;
            float a = bb + w0 * pts[pp] + w1 * pts[33 + pp] + w2 * pts[66 + pp];
            h0[o * 36 + pp] = fmaxf(a, 0.0f);
        }
    }
    __syncthreads();
    {
        float acc[8];
        #pragma unroll
        for (int p = 0; p < 8; ++p) acc[p] = b1s[o];
        for (int i = 0; i < 64; ++i) {
            float w = BUF[256 + i * 64 + o];
            float4 ha = *(const float4*)&h0[i * 36 + pg * 8];
            float4 hb = *(const float4*)&h0[i * 36 + pg * 8 + 4];
            acc[0] += w * ha.x; acc[1] += w * ha.y; acc[2] += w * ha.z; acc[3] += w * ha.w;
            acc[4] += w * hb.x; acc[5] += w * hb.y; acc[6] += w * hb.z; acc[7] += w * hb.w;
        }
        #pragma unroll
        for (int p = 0; p < 8; ++p) h1s[o * 36 + pg * 8 + p] = fmaxf(acc[p], 0.0f);
    }
    __syncthreads();
    {
        const float* W2 = sW2 + (size_t)s * 8192;
        int o2 = t & 127, q = t >> 7;
        #pragma unroll
        for (int r = 0; r < 8; ++r) {
            float4 w = *(const float4*)(W2 + o2 * 64 + q * 32 + r * 4);
            int i = q * 32 + r * 4;
            BUF[(i + 0) * 128 + o2] = w.x;
            BUF[(i + 1) * 128 + o2] = w.y;
            BUF[(i + 2) * 128 + o2] = w.z;
            BUF[(i + 3) * 128 + o2] = w.w;
        }
    }
    __syncthreads();
    {
        int o2 = t & 127, ph = t >> 7;
        float acc[16];
        #pragma unroll
        for (int p = 0; p < 16; ++p) acc[p] = b2s[o2];
        for (int i = 0; i < 64; ++i) {
            float w = BUF[i * 128 + o2];
            float4 ha = *(const float4*)&h1s[i * 36 + ph * 16];
            float4 hb = *(const float4*)&h1s[i * 36 + ph * 16 + 4];
            float4 hc = *(const float4*)&h1s[i * 36 + ph * 16 + 8];
            float4 hd = *(const float4*)&h1s[i * 36 + ph * 16 + 12];
            acc[0]  += w * ha.x; acc[1]  += w * ha.y; acc[2]  += w * ha.z; acc[3]  += w * ha.w;
            acc[4]  += w * hb.x; acc[5]  += w * hb.y; acc[6]  += w * hb.z; acc[7]  += w * hb.w;
            acc[8]  += w * hc.x; acc[9]  += w * hc.y; acc[10] += w * hc.z; acc[11] += w * hc.w;
            acc[12] += w * hd.x; acc[13] += w * hd.y; acc[14] += w * hd.z; acc[15] += w * hd.w;
        }
        #pragma unroll
        for (int p = 0; p < 16; ++p) {
            int j = j0 + ph * 16 + p;
            F[((size_t)b * NPTS + j) * 384 + s * 128 + o2] = f2bf(fmaxf(acc[p], 0.0f));
        }
    }
}

// ---------------- Kernel 3: gather-max (bf16 in/out), point [b][n][384] ------
// uint16 compare valid: post-relu bf16 (>=0) bit patterns are value-monotone.
__global__ __launch_bounds__(384) void maxgather_bf16(
    const unsigned short* __restrict__ F, const int* __restrict__ knn,
    unsigned short* __restrict__ pt)
{
    __shared__ int idxS[KNN];
    const int q = blockIdx.x;            // b*4096 + n
    const int b = q >> 12;
    const int t = threadIdx.x;           // channel 0..383
    if (t < KNN) idxS[t] = knn[(size_t)q * KNN + t];
    __syncthreads();
    const unsigned short* Fb = F + (size_t)b * NPTS * 384;
    unsigned short m = 0;
    #pragma unroll 8
    for (int k = 0; k < KNN; ++k) {
        unsigned short v = Fb[(size_t)idxS[k] * 384 + t];
        m = (v > m) ? v : m;
    }
    pt[(size_t)q * 384 + t] = m;
}

// ---------------- Kernel 4: bf16 MFMA GEMM + bias + relu ---------------------
// C[b] = relu(W[M][K] (fp32, cvt in staging) * B^T[b][n][K] (bf16) + bias)
// OUT_FP32=0: out bf16 [b][n][M] (transposed, feeds next GEMM)
// OUT_FP32=1: out fp32 [b][m][4096]
template<int OUT_FP32>
__global__ __launch_bounds__(256) void gemm_bf16(
    const float* __restrict__ W, const unsigned short* __restrict__ Bt,
    const float* __restrict__ bias, void* __restrict__ outp,
    int M, int K)
{
    __shared__ __align__(16) unsigned short As[128 * 40]; // [m][k] pad 40
    __shared__ __align__(16) unsigned short Bs[128 * 40]; // [n][k] pad 40
    __shared__ float biasS[128];

    const int t = threadIdx.x;
    const int b = blockIdx.z;
    const int m0 = blockIdx.x * 128;
    const int n0 = blockIdx.y * 128;
    if (t < 128) biasS[t] = bias[m0 + t];

    const int wave = t >> 6, lane = t & 63, quad = lane >> 4, l15 = lane & 15;
    const int wr = wave >> 1, wc = wave & 1;

    const int am = t & 127, akh = t >> 7;            // A: row m, k-half (16)
    const float* Wp = W + (size_t)(m0 + am) * K + akh * 16;
    const int bn = t >> 2, bq = t & 3;               // B: 4 thr per n-row
    const unsigned short* Bp = Bt + ((size_t)b * NPTS + n0) * K;

    floatx4 acc[16];
    #pragma unroll
    for (int i = 0; i < 16; ++i) acc[i] = (floatx4){0.f, 0.f, 0.f, 0.f};

    const int nk = K >> 5;
    for (int kt = 0; kt < nk; ++kt) {
        const int k0 = kt << 5;
        float4 a0 = *(const float4*)(Wp + k0);
        float4 a1 = *(const float4*)(Wp + k0 + 4);
        float4 a2 = *(const float4*)(Wp + k0 + 8);
        float4 a3 = *(const float4*)(Wp + k0 + 12);
        uint4 bv0 = *(const uint4*)(Bp + (size_t)bn * K + k0 + bq * 8);
        uint4 bv1 = *(const uint4*)(Bp + (size_t)(bn + 64) * K + k0 + bq * 8);
        __syncthreads();
        {
            unsigned short aw[16];
            aw[0] = f2bf(a0.x); aw[1] = f2bf(a0.y); aw[2] = f2bf(a0.z); aw[3] = f2bf(a0.w);
            aw[4] = f2bf(a1.x); aw[5] = f2bf(a1.y); aw[6] = f2bf(a1.z); aw[7] = f2bf(a1.w);
            aw[8] = f2bf(a2.x); aw[9] = f2bf(a2.y); aw[10] = f2bf(a2.z); aw[11] = f2bf(a2.w);
            aw[12] = f2bf(a3.x); aw[13] = f2bf(a3.y); aw[14] = f2bf(a3.z); aw[15] = f2bf(a3.w);
            uint4* dst = (uint4*)&As[am * 40 + akh * 16];
            dst[0] = *(const uint4*)&aw[0];
            dst[1] = *(const uint4*)&aw[8];
            *(uint4*)&Bs[bn * 40 + bq * 8] = bv0;
            *(uint4*)&Bs[(bn + 64) * 40 + bq * 8] = bv1;
        }
        __syncthreads();
        short8 af[4], bfv[4];
        #pragma unroll
        for (int i = 0; i < 4; ++i)
            af[i] = *(const short8*)&As[(wr * 64 + i * 16 + l15) * 40 + quad * 8];
        #pragma unroll
        for (int j = 0; j < 4; ++j)
            bfv[j] = *(const short8*)&Bs[(wc * 64 + j * 16 + l15) * 40 + quad * 8];
        #pragma unroll
        for (int i = 0; i < 4; ++i)
            #pragma unroll
            for (int j = 0; j < 4; ++j)
                acc[i * 4 + j] = __builtin_amdgcn_mfma_f32_16x16x32_bf16(
                    af[i], bfv[j], acc[i * 4 + j], 0, 0, 0);
    }

    #pragma unroll
    for (int i = 0; i < 4; ++i) {
        const int mbase = wr * 64 + i * 16 + quad * 4;   // local m for reg r
        #pragma unroll
        for (int j = 0; j < 4; ++j) {
            const int n = n0 + wc * 64 + j * 16 + l15;
            float v0 = fmaxf(acc[i * 4 + j][0] + biasS[mbase + 0], 0.f);
            float v1 = fmaxf(acc[i * 4 + j][1] + biasS[mbase + 1], 0.f);
            float v2 = fmaxf(acc[i * 4 + j][2] + biasS[mbase + 2], 0.f);
            float v3 = fmaxf(acc[i * 4 + j][3] + biasS[mbase + 3], 0.f);
            if (OUT_FP32) {
                float* o = (float*)outp + ((size_t)b * M + m0 + mbase) * NPTS + n;
                o[0 * NPTS] = v0; o[1 * NPTS] = v1; o[2 * NPTS] = v2; o[3 * NPTS] = v3;
            } else {
                ushort4 pk;
                pk.x = f2bf(v0); pk.y = f2bf(v1); pk.z = f2bf(v2); pk.w = f2bf(v3);
                *(ushort4*)((unsigned short*)outp +
                            ((size_t)b * NPTS + n) * M + m0 + mbase) = pk;
            }
        }
    }
}

// ---------------- Kernel 5: column max of gft [b][n][1024] -> gfeat ---------
// atomicMax on float bits (valid: values >= 0; poison 0xAA.. is negative int)
__global__ __launch_bounds__(256) void rowmax_bf16(const unsigned short* __restrict__ gft,
                                                   float* __restrict__ outv)
{
    const int b = blockIdx.x >> 4, chunk = blockIdx.x & 15;
    const int t = threadIdx.x;
    const ushort4* base = (const ushort4*)(gft + ((size_t)b * NPTS + chunk * 256) * 1024);
    float m0 = 0.f, m1 = 0.f, m2 = 0.f, m3 = 0.f;
    for (int n = 0; n < 256; ++n) {
        ushort4 v = base[(size_t)n * 256 + t];
        m0 = fmaxf(m0, bf2f(v.x));
        m1 = fmaxf(m1, bf2f(v.y));
        m2 = fmaxf(m2, bf2f(v.z));
        m3 = fmaxf(m3, bf2f(v.w));
    }
    int* o = (int*)&outv[(size_t)b * 1024 + t * 4];
    atomicMax(o + 0, __float_as_int(m0));
    atomicMax(o + 1, __float_as_int(m1));
    atomicMax(o + 2, __float_as_int(m2));
    atomicMax(o + 3, __float_as_int(m3));
}

extern "C" void kernel_launch(void* const* d_in, const int* in_sizes, int n_in,
                              void* d_out, int out_size, void* d_ws, size_t ws_size,
                              hipStream_t stream)
{
    const float* x   = (const float*)d_in[0];
    const float* sW0 = (const float*)d_in[1];
    const float* sb0 = (const float*)d_in[2];
    const float* sW1 = (const float*)d_in[3];
    const float* sb1 = (const float*)d_in[4];
    const float* sW2 = (const float*)d_in[5];
    const float* sb2 = (const float*)d_in[6];
    const float* gW0 = (const float*)d_in[7];
    const float* gb0 = (const float*)d_in[8];
    const float* gW1 = (const float*)d_in[9];
    const float* gb1 = (const float*)d_in[10];
    const float* mW0 = (const float*)d_in[11];
    const float* mb0 = (const float*)d_in[12];
    const float* mW1 = (const float*)d_in[13];
    const float* mb1 = (const float*)d_in[14];
    float* outp = (float*)d_out;

    char* ws = (char*)d_ws;
    int*            idx     = (int*)(ws);                        // 2 MB
    float4*         pts4    = (float4*)(ws + 2097152u);          // 256 KB
    unsigned short* F       = (unsigned short*)(ws + 4194304u);  // 12.6 MB [b][n][384] bf16
    unsigned short* point_t = (unsigned short*)(ws + 18874368u); // 12.6 MB [b][n][384] bf16
    unsigned short* gf0t    = (unsigned short*)(ws + 33554432u); // 8.4 MB  [b][n][256] bf16
    unsigned short* gft     = (unsigned short*)(ws + 50331648u); // 33.6 MB [b][n][1024] bf16
    unsigned short* msf0t   = (unsigned short*)(ws + 100663296u);// 8.4 MB  [b][n][256] bf16

    prep_pts<<<dim3(64), dim3(256), 0, stream>>>(x, pts4);
    knn_kernel7<<<dim3(16384), dim3(256), 0, stream>>>(pts4, idx);
    pointmlp_kernel<<<dim3(512, 3), dim3(256), 0, stream>>>(
        x, sW0, sb0, sW1, sb1, sW2, sb2, F);
    maxgather_bf16<<<dim3(16384), dim3(384), 0, stream>>>(F, idx, point_t);
    gemm_bf16<0><<<dim3(2, 32, 4), dim3(256), 0, stream>>>(gW0, point_t, gb0, gf0t, 256, 384);
    gemm_bf16<0><<<dim3(8, 32, 4), dim3(256), 0, stream>>>(gW1, gf0t, gb1, gft, 1024, 256);
    rowmax_bf16<<<dim3(64), dim3(256), 0, stream>>>(gft, outp);
    gemm_bf16<0><<<dim3(2, 32, 4), dim3(256), 0, stream>>>(mW0, gft, mb0, msf0t, 256, 1024);
    gemm_bf16<1><<<dim3(1, 32, 4), dim3(256), 0, stream>>>(mW1, msf0t, mb1, outp + 4096, 128, 256);
}

// Round 10
// 322.859 us; speedup vs baseline: 3.1059x; 1.1427x over previous
//
#include <hip/hip_runtime.h>
#include <hip/hip_bf16.h>

#define NPTS 4096
#define KNN  32

typedef __attribute__((ext_vector_type(8))) short short8;
typedef __attribute__((ext_vector_type(4))) float floatx4;

__device__ __forceinline__ unsigned short f2bf(float f) {
    unsigned u = __float_as_uint(f);
    u = (u + 0x7FFFu + ((u >> 16) & 1u)) >> 16;
    return (unsigned short)u;
}
__device__ __forceinline__ float bf2f(unsigned short v) {
    return __uint_as_float(((unsigned)v) << 16);
}

// ---------------- Kernel 0: pack points + convert weights to bf16 ------------
// blocks [0,64): pts4 = (x,y,z,|p|^2). blocks [64,2624): fp32->bf16 weights
// (gW0 98304 | gW1 262144 | mW0 262144 | mW1 32768 = 655360 elems).
__global__ __launch_bounds__(256) void prep_all(
    const float* __restrict__ x, float4* __restrict__ pts4,
    const float* __restrict__ gW0, const float* __restrict__ gW1,
    const float* __restrict__ mW0, const float* __restrict__ mW1,
    unsigned short* __restrict__ Wb0, unsigned short* __restrict__ Wb1,
    unsigned short* __restrict__ Wb2, unsigned short* __restrict__ Wb3)
{
    const int blk = blockIdx.x, t = threadIdx.x;
    if (blk < 64) {
        const int i = blk * 256 + t;                 // 0..16383 = b*4096+n
        const int b = i >> 12, n = i & (NPTS - 1);
        const float* xb = x + (size_t)b * 3 * NPTS;
        const float qx = xb[n], qy = xb[NPTS + n], qz = xb[2 * NPTS + n];
        pts4[i] = make_float4(qx, qy, qz, qx * qx + qy * qy + qz * qz);
    } else {
        const int wi = (blk - 64) * 256 + t;         // 0..655359 (exact)
        float v; unsigned short* dst;
        if (wi < 98304)       { v = gW0[wi];          dst = Wb0 + wi; }
        else if (wi < 360448) { v = gW1[wi - 98304];  dst = Wb1 + (wi - 98304); }
        else if (wi < 622592) { v = mW0[wi - 360448]; dst = Wb2 + (wi - 360448); }
        else                  { v = mW1[wi - 622592]; dst = Wb3 + (wi - 622592); }
        *dst = f2bf(v);
    }
}

// ---------------- Kernel 1: exact KNN, block per query (R8-passing) ----------
// 16 keys/thread in registers. Fixed 15-iteration binary search (rolled loop,
// one barrier/iteration) on the top-16 key bits over [0x8000, 0xFF7F] (width
// 0x7F80 <= 2^15 -> width 1 after 15 halvings; covers all finite distances).
// Collected set {key <= (V<<16)|0xFFFF} is a superset of the top-33; exact
// (key,idx) parallel ranking; ranks 1..32 emitted (rank 0 = self dropped).
// Matches jax top_k incl. tie order.
__global__ __launch_bounds__(256) void knn_kernel7(const float4* __restrict__ pts4,
                                                   int* __restrict__ knn_out)
{
    __shared__ unsigned sred[2][4];
    __shared__ unsigned long long C[96];
    __shared__ unsigned ccnt;

    const int t = threadIdx.x, wid = t >> 6, lane = t & 63;
    const int q = blockIdx.x, b = q >> 12, n = q & (NPTS - 1);
    const float4* P = pts4 + ((size_t)b << 12);
    const float4 s = P[n];
    const float px = s.x, py = s.y, pz = s.z, sqn = s.w;

    if (t == 0) ccnt = 0u;

    unsigned key[16];
    #pragma unroll
    for (int g = 0; g < 4; ++g) {
        float4 c0 = P[((g * 4 + 0) << 8) + t];
        float4 c1 = P[((g * 4 + 1) << 8) + t];
        float4 c2 = P[((g * 4 + 2) << 8) + t];
        float4 c3 = P[((g * 4 + 3) << 8) + t];
        float d0 = (sqn + c0.w) - 2.0f * (px * c0.x + py * c0.y + pz * c0.z);
        float d1 = (sqn + c1.w) - 2.0f * (px * c1.x + py * c1.y + pz * c1.z);
        float d2 = (sqn + c2.w) - 2.0f * (px * c2.x + py * c2.y + pz * c2.z);
        float d3 = (sqn + c3.w) - 2.0f * (px * c3.x + py * c3.y + pz * c3.z);
        unsigned u0 = __float_as_uint(d0), u1 = __float_as_uint(d1);
        unsigned u2 = __float_as_uint(d2), u3 = __float_as_uint(d3);
        key[g * 4 + 0] = (u0 & 0x80000000u) ? ~u0 : (u0 | 0x80000000u);
        key[g * 4 + 1] = (u1 & 0x80000000u) ? ~u1 : (u1 | 0x80000000u);
        key[g * 4 + 2] = (u2 & 0x80000000u) ? ~u2 : (u2 | 0x80000000u);
        key[g * 4 + 3] = (u3 & 0x80000000u) ? ~u3 : (u3 | 0x80000000u);
    }

    unsigned lo = 0x8000u, hi = 0xFF7Fu;
    for (int it = 0; it < 15; ++it) {
        const unsigned mid = (lo + hi) >> 1;
        const unsigned thr = (mid << 16) | 0xFFFFu;
        unsigned c = 0;
        #pragma unroll
        for (int r = 0; r < 16; ++r)
            c += (unsigned)__popcll(__ballot(key[r] <= thr));
        if (lane == 0) sred[it & 1][wid] = c;
        __syncthreads();
        const unsigned g = sred[it & 1][0] + sred[it & 1][1] +
                           sred[it & 1][2] + sred[it & 1][3];
        if (g >= 33u) hi = mid; else lo = mid + 1u;
    }
    const unsigned thrF = (lo << 16) | 0xFFFFu;

    #pragma unroll
    for (int r = 0; r < 16; ++r) {
        if (key[r] <= thrF) {
            unsigned p = atomicAdd(&ccnt, 1u);
            if (p < 96u)
                C[p] = ((unsigned long long)key[r] << 32) |
                       (unsigned)((r << 8) + t);
        }
    }
    __syncthreads();

    int nc = (int)ccnt; if (nc > 96) nc = 96;
    if (t < nc) {
        const unsigned long long me = C[t];
        int rank = 0;
        for (int j = 0; j < nc; ++j) rank += (C[j] < me) ? 1 : 0;
        if (rank >= 1 && rank <= KNN)
            knn_out[(size_t)q * KNN + (rank - 1)] = (int)(me & 0xFFFFFFFFu);
    }
}

// ---------------- Kernel 2: per-point 3-layer MLP -> F bf16 [b][n][384] ------
__global__ __launch_bounds__(256) void pointmlp_kernel(
    const float* __restrict__ x,
    const float* __restrict__ sW0, const float* __restrict__ sb0,
    const float* __restrict__ sW1, const float* __restrict__ sb1,
    const float* __restrict__ sW2, const float* __restrict__ sb2,
    unsigned short* __restrict__ F)
{
    __shared__ __align__(16) float BUF[8192];
    __shared__ __align__(16) float h1s[64 * 36];
    __shared__ float b1s[64];
    __shared__ float b2s[128];
    __shared__ float pts[3 * 33];

    const int t = threadIdx.x;
    const int s = blockIdx.y;
    const int tile = blockIdx.x;
    const int b = tile >> 7;
    const int j0 = (tile & 127) << 5;
    const float* xb = x + (size_t)b * 3 * NPTS;

    if (t < 192) BUF[t] = sW0[s * 192 + t];
    else if (t < 256) BUF[t] = sb0[s * 64 + (t - 192)];
    if (t < 64) b1s[t] = sb1[s * 64 + t];
    if (t < 128) b2s[t] = sb2[s * 128 + t];
    if (t < 96) { int c = t >> 5, p = t & 31; pts[c * 33 + p] = xb[c * NPTS + j0 + p]; }
    {
        const float* W1 = sW1 + (size_t)s * 4096;
        int o = t & 63, q = t >> 6;
        #pragma unroll
        for (int r = 0; r < 4; ++r) {
            float4 w = *(const float4*)(W1 + o * 64 + q * 16 + r * 4);
            int i = q * 16 + r * 4;
            BUF[256 + (i + 0) * 64 + o] = w.x;
            BUF[256 + (i + 1) * 64 + o] = w.y;
            BUF[256 + (i + 2) * 64 + o] = w.z;
            BUF[256 + (i + 3) * 64 + o] = w.w;
        }
    }
    __syncthreads();
    const int o = t & 63, pg = t >> 6;
    float* h0 = BUF + 4352;
    {
        float w0 = BUF[o * 3], w1 = BUF[o * 3 + 1], w2 = BUF[o * 3 + 2], bb = BUF[192 + o];
        #pragma unroll
        for (int p = 0; p < 8; ++p) {
            int pp = pg * 8 + p;
            float a = bb + w0 * pts[pp] + w1 * pts[33 + pp] + w2 * pts[66 + pp];
            h0[o * 36 + pp] = fmaxf(a, 0.0f);
        }
    }
    __syncthreads();
    {
        float acc[8];
        #pragma unroll
        for (int p = 0; p < 8; ++p) acc[p] = b1s[o];
        for (int i = 0; i < 64; ++i) {
            float w = BUF[256 + i * 64 + o];
            float4 ha = *(const float4*)&h0[i * 36 + pg * 8];
            float4 hb = *(const float4*)&h0[i * 36 + pg * 8 + 4];
            acc[0] += w * ha.x; acc[1] += w * ha.y; acc[2] += w * ha.z; acc[3] += w * ha.w;
            acc[4] += w * hb.x; acc[5] += w * hb.y; acc[6] += w * hb.z; acc[7] += w * hb.w;
        }
        #pragma unroll
        for (int p = 0; p < 8; ++p) h1s[o * 36 + pg * 8 + p] = fmaxf(acc[p], 0.0f);
    }
    __syncthreads();
    {
        const float* W2 = sW2 + (size_t)s * 8192;
        int o2 = t & 127, q = t >> 7;
        #pragma unroll
        for (int r = 0; r < 8; ++r) {
            float4 w = *(const float4*)(W2 + o2 * 64 + q * 32 + r * 4);
            int i = q * 32 + r * 4;
            BUF[(i + 0) * 128 + o2] = w.x;
            BUF[(i + 1) * 128 + o2] = w.y;
            BUF[(i + 2) * 128 + o2] = w.z;
            BUF[(i + 3) * 128 + o2] = w.w;
        }
    }
    __syncthreads();
    {
        int o2 = t & 127, ph = t >> 7;
        float acc[16];
        #pragma unroll
        for (int p = 0; p < 16; ++p) acc[p] = b2s[o2];
        for (int i = 0; i < 64; ++i) {
            float w = BUF[i * 128 + o2];
            float4 ha = *(const float4*)&h1s[i * 36 + ph * 16];
            float4 hb = *(const float4*)&h1s[i * 36 + ph * 16 + 4];
            float4 hc = *(const float4*)&h1s[i * 36 + ph * 16 + 8];
            float4 hd = *(const float4*)&h1s[i * 36 + ph * 16 + 12];
            acc[0]  += w * ha.x; acc[1]  += w * ha.y; acc[2]  += w * ha.z; acc[3]  += w * ha.w;
            acc[4]  += w * hb.x; acc[5]  += w * hb.y; acc[6]  += w * hb.z; acc[7]  += w * hb.w;
            acc[8]  += w * hc.x; acc[9]  += w * hc.y; acc[10] += w * hc.z; acc[11] += w * hc.w;
            acc[12] += w * hd.x; acc[13] += w * hd.y; acc[14] += w * hd.z; acc[15] += w * hd.w;
        }
        #pragma unroll
        for (int p = 0; p < 16; ++p) {
            int j = j0 + ph * 16 + p;
            F[((size_t)b * NPTS + j) * 384 + s * 128 + o2] = f2bf(fmaxf(acc[p], 0.0f));
        }
    }
}

// ---------------- Kernel 3: gather-max (bf16 in/out), point [b][n][384] ------
__global__ __launch_bounds__(384) void maxgather_bf16(
    const unsigned short* __restrict__ F, const int* __restrict__ knn,
    unsigned short* __restrict__ pt)
{
    __shared__ int idxS[KNN];
    const int q = blockIdx.x;            // b*4096 + n
    const int b = q >> 12;
    const int t = threadIdx.x;           // channel 0..383
    if (t < KNN) idxS[t] = knn[(size_t)q * KNN + t];
    __syncthreads();
    const unsigned short* Fb = F + (size_t)b * NPTS * 384;
    unsigned short m = 0;
    #pragma unroll 8
    for (int k = 0; k < KNN; ++k) {
        unsigned short v = Fb[(size_t)idxS[k] * 384 + t];
        m = (v > m) ? v : m;
    }
    pt[(size_t)q * 384 + t] = m;
}

// ---------------- Kernel 4: bf16 MFMA GEMM + bias + relu ---------------------
// C[b] = relu(Wb[M][K] (bf16, pre-converted) * B^T[b][n][K] (bf16) + bias)
// OUT_FP32=0: out bf16 [b][n][M]; OUT_FP32=1: out fp32 [b][m][4096].
// DO_ROWMAX=1: additionally gfeat[b][m] = max_n out (pre-bf16-round fp32),
// via j-pre-reduced LDS atomicMax + 128 global atomicMax per block.
template<int OUT_FP32, int DO_ROWMAX>
__global__ __launch_bounds__(256) void gemm_bf16(
    const unsigned short* __restrict__ Wb, const unsigned short* __restrict__ Bt,
    const float* __restrict__ bias, void* __restrict__ outp,
    float* __restrict__ gfeat, int M, int K)
{
    __shared__ __align__(16) unsigned short As[128 * 40]; // [m][k] pad 40
    __shared__ __align__(16) unsigned short Bs[128 * 40]; // [n][k] pad 40
    __shared__ float biasS[128];
    __shared__ int redI[128];

    const int t = threadIdx.x;
    const int b = blockIdx.z;
    const int m0 = blockIdx.x * 128;
    const int n0 = blockIdx.y * 128;
    if (t < 128) biasS[t] = bias[m0 + t];
    if (DO_ROWMAX && t < 128) redI[t] = 0;

    const int wave = t >> 6, lane = t & 63, quad = lane >> 4, l15 = lane & 15;
    const int wr = wave >> 1, wc = wave & 1;

    const int am = t & 127, akh = t >> 7;            // A: row m, k-half (16)
    const unsigned short* Wp = Wb + (size_t)(m0 + am) * K + akh * 16;
    const int bn = t >> 2, bq = t & 3;               // B: 4 thr per n-row
    const unsigned short* Bp = Bt + ((size_t)b * NPTS + n0) * K;

    floatx4 acc[16];
    #pragma unroll
    for (int i = 0; i < 16; ++i) acc[i] = (floatx4){0.f, 0.f, 0.f, 0.f};

    const int nk = K >> 5;
    for (int kt = 0; kt < nk; ++kt) {
        const int k0 = kt << 5;
        uint4 av0 = *(const uint4*)(Wp + k0);        // 8 bf16
        uint4 av1 = *(const uint4*)(Wp + k0 + 8);    // 8 bf16
        uint4 bv0 = *(const uint4*)(Bp + (size_t)bn * K + k0 + bq * 8);
        uint4 bv1 = *(const uint4*)(Bp + (size_t)(bn + 64) * K + k0 + bq * 8);
        __syncthreads();
        {
            uint4* dst = (uint4*)&As[am * 40 + akh * 16];
            dst[0] = av0;
            dst[1] = av1;
            *(uint4*)&Bs[bn * 40 + bq * 8] = bv0;
            *(uint4*)&Bs[(bn + 64) * 40 + bq * 8] = bv1;
        }
        __syncthreads();
        short8 af[4], bfv[4];
        #pragma unroll
        for (int i = 0; i < 4; ++i)
            af[i] = *(const short8*)&As[(wr * 64 + i * 16 + l15) * 40 + quad * 8];
        #pragma unroll
        for (int j = 0; j < 4; ++j)
            bfv[j] = *(const short8*)&Bs[(wc * 64 + j * 16 + l15) * 40 + quad * 8];
        #pragma unroll
        for (int i = 0; i < 4; ++i)
            #pragma unroll
            for (int j = 0; j < 4; ++j)
                acc[i * 4 + j] = __builtin_amdgcn_mfma_f32_16x16x32_bf16(
                    af[i], bfv[j], acc[i * 4 + j], 0, 0, 0);
    }

    #pragma unroll
    for (int i = 0; i < 4; ++i) {
        const int mbase = wr * 64 + i * 16 + quad * 4;   // local m rows
        float rm0 = 0.f, rm1 = 0.f, rm2 = 0.f, rm3 = 0.f;
        #pragma unroll
        for (int j = 0; j < 4; ++j) {
            const int n = n0 + wc * 64 + j * 16 + l15;
            float v0 = fmaxf(acc[i * 4 + j][0] + biasS[mbase + 0], 0.f);
            float v1 = fmaxf(acc[i * 4 + j][1] + biasS[mbase + 1], 0.f);
            float v2 = fmaxf(acc[i * 4 + j][2] + biasS[mbase + 2], 0.f);
            float v3 = fmaxf(acc[i * 4 + j][3] + biasS[mbase + 3], 0.f);
            if (DO_ROWMAX) {
                rm0 = fmaxf(rm0, v0); rm1 = fmaxf(rm1, v1);
                rm2 = fmaxf(rm2, v2); rm3 = fmaxf(rm3, v3);
            }
            if (OUT_FP32) {
                float* o = (float*)outp + ((size_t)b * M + m0 + mbase) * NPTS + n;
                o[0 * NPTS] = v0; o[1 * NPTS] = v1; o[2 * NPTS] = v2; o[3 * NPTS] = v3;
            } else {
                ushort4 pk;
                pk.x = f2bf(v0); pk.y = f2bf(v1); pk.z = f2bf(v2); pk.w = f2bf(v3);
                *(ushort4*)((unsigned short*)outp +
                            ((size_t)b * NPTS + n) * M + m0 + mbase) = pk;
            }
        }
        if (DO_ROWMAX) {   // values >= 0 -> int-bit compare == float compare
            atomicMax(&redI[mbase + 0], __float_as_int(rm0));
            atomicMax(&redI[mbase + 1], __float_as_int(rm1));
            atomicMax(&redI[mbase + 2], __float_as_int(rm2));
            atomicMax(&redI[mbase + 3], __float_as_int(rm3));
        }
    }
    if (DO_ROWMAX) {
        __syncthreads();
        if (t < 128)       // d_out poison 0xAA.. is negative int -> always lose
            atomicMax((int*)&gfeat[(size_t)b * 1024 + m0 + t], redI[t]);
    }
}

extern "C" void kernel_launch(void* const* d_in, const int* in_sizes, int n_in,
                              void* d_out, int out_size, void* d_ws, size_t ws_size,
                              hipStream_t stream)
{
    const float* x   = (const float*)d_in[0];
    const float* sW0 = (const float*)d_in[1];
    const float* sb0 = (const float*)d_in[2];
    const float* sW1 = (const float*)d_in[3];
    const float* sb1 = (const float*)d_in[4];
    const float* sW2 = (const float*)d_in[5];
    const float* sb2 = (const float*)d_in[6];
    const float* gW0 = (const float*)d_in[7];
    const float* gb0 = (const float*)d_in[8];
    const float* gW1 = (const float*)d_in[9];
    const float* gb1 = (const float*)d_in[10];
    const float* mW0 = (const float*)d_in[11];
    const float* mb0 = (const float*)d_in[12];
    const float* mW1 = (const float*)d_in[13];
    const float* mb1 = (const float*)d_in[14];
    float* outp = (float*)d_out;

    char* ws = (char*)d_ws;
    int*            idx     = (int*)(ws);                        // 2 MB
    float4*         pts4    = (float4*)(ws + 2097152u);          // 256 KB
    unsigned short* Wb0     = (unsigned short*)(ws + 2359296u);  // 192 KB  gW0 bf16
    unsigned short* Wb1     = (unsigned short*)(ws + 2555904u);  // 512 KB  gW1 bf16
    unsigned short* Wb2     = (unsigned short*)(ws + 3080192u);  // 512 KB  mW0 bf16
    unsigned short* Wb3     = (unsigned short*)(ws + 3604480u);  // 64 KB   mW1 bf16
    unsigned short* F       = (unsigned short*)(ws + 4194304u);  // 12.6 MB [b][n][384] bf16
    unsigned short* point_t = (unsigned short*)(ws + 18874368u); // 12.6 MB [b][n][384] bf16
    unsigned short* gf0t    = (unsigned short*)(ws + 33554432u); // 8.4 MB  [b][n][256] bf16
    unsigned short* gft     = (unsigned short*)(ws + 50331648u); // 33.6 MB [b][n][1024] bf16
    unsigned short* msf0t   = (unsigned short*)(ws + 100663296u);// 8.4 MB  [b][n][256] bf16

    prep_all<<<dim3(2624), dim3(256), 0, stream>>>(
        x, pts4, gW0, gW1, mW0, mW1, Wb0, Wb1, Wb2, Wb3);
    knn_kernel7<<<dim3(16384), dim3(256), 0, stream>>>(pts4, idx);
    pointmlp_kernel<<<dim3(512, 3), dim3(256), 0, stream>>>(
        x, sW0, sb0, sW1, sb1, sW2, sb2, F);
    maxgather_bf16<<<dim3(16384), dim3(384), 0, stream>>>(F, idx, point_t);
    gemm_bf16<0, 0><<<dim3(2, 32, 4), dim3(256), 0, stream>>>(
        Wb0, point_t, gb0, gf0t, nullptr, 256, 384);
    gemm_bf16<0, 1><<<dim3(8, 32, 4), dim3(256), 0, stream>>>(
        Wb1, gf0t, gb1, gft, outp, 1024, 256);
    gemm_bf16<0, 0><<<dim3(2, 32, 4), dim3(256), 0, stream>>>(
        Wb2, gft, mb0, msf0t, nullptr, 256, 1024);
    gemm_bf16<1, 0><<<dim3(1, 32, 4), dim3(256), 0, stream>>>(
        Wb3, msf0t, mb1, outp + 4096, nullptr, 128, 256);
}